// Round 1
// baseline (1183.965 us; speedup 1.0000x reference)
//
#include <hip/hip_runtime.h>

// GCN: h1 = x@W1; agg1 = scatter(norm*h1) + b1; relu
//      h2 = relu(agg1)@W2; agg2 = scatter(norm*h2) + b2; relu
//      out = relu(agg2)@Wfc + bfc
// All fp32. Self-loop + bias folded into the init kernel (no atomics for them).

__global__ void k_deg_init(float* deg, int n) {
    int i = blockIdx.x * blockDim.x + threadIdx.x;
    if (i < n) deg[i] = 1.0f;  // self-loop contributes 1
}

__global__ void k_deg_count(const int* __restrict__ dst, int e, float* deg) {
    int i = blockIdx.x * blockDim.x + threadIdx.x;
    if (i < e) atomicAdd(&deg[dst[i]], 1.0f);
}

__global__ void k_rsqrt(float* deg, int n) {
    int i = blockIdx.x * blockDim.x + threadIdx.x;
    if (i < n) deg[i] = rsqrtf(deg[i]);  // deg >= 1 always (self-loops)
}

// Wave-per-row GEMM: X [n,K] @ W [K,64] -> H [n,64]. W staged in LDS.
// Lane c accumulates column c; x row broadcast via __shfl.
template<int K, bool RELU_IN>
__global__ void k_gemm(const float* __restrict__ X, const float* __restrict__ W,
                       float* __restrict__ H, int n) {
    __shared__ float ws[K * 64];
    for (int idx = threadIdx.x; idx < K * 64; idx += blockDim.x) ws[idx] = W[idx];
    __syncthreads();

    int lane  = threadIdx.x & 63;
    int wave  = threadIdx.x >> 6;
    int wpb   = blockDim.x >> 6;
    int gwave = blockIdx.x * wpb + wave;
    int nwav  = gridDim.x * wpb;

    for (int row = gwave; row < n; row += nwav) {
        const float* xr = X + (size_t)row * K;
        float acc = 0.f;
        if (K == 128) {
            float2 xv = ((const float2*)xr)[lane];  // x[2l], x[2l+1]
            if (RELU_IN) { xv.x = fmaxf(xv.x, 0.f); xv.y = fmaxf(xv.y, 0.f); }
            #pragma unroll 8
            for (int kk = 0; kk < 64; ++kk) {
                float xa = __shfl(xv.x, kk);
                float xb = __shfl(xv.y, kk);
                acc += xa * ws[(2 * kk) * 64 + lane];
                acc += xb * ws[(2 * kk + 1) * 64 + lane];
            }
        } else {  // K == 64
            float xv = xr[lane];
            if (RELU_IN) xv = fmaxf(xv, 0.f);
            #pragma unroll 8
            for (int kk = 0; kk < 64; ++kk) {
                acc += __shfl(xv, kk) * ws[kk * 64 + lane];
            }
        }
        H[(size_t)row * 64 + lane] = acc;
    }
}

// agg[i][c] = b[c] + h[i][c] * dis[i]^2   (bias + self-loop edge, norm=dis^2)
__global__ void k_init(const float* __restrict__ h, const float* __restrict__ dis,
                       const float* __restrict__ b, float* __restrict__ agg, int n) {
    int tid = blockIdx.x * blockDim.x + threadIdx.x;
    if (tid < n * 64) {
        int i = tid >> 6, c = tid & 63;
        float d = dis[i];
        agg[tid] = b[c] + h[tid] * d * d;
    }
}

// Wave per edge: lane c handles channel c. agg[dst] += h[src] * dis[src]*dis[dst]
__global__ void k_scatter(const int* __restrict__ src, const int* __restrict__ dst,
                          const float* __restrict__ dis, const float* __restrict__ h,
                          float* agg, int e) {
    int lane  = threadIdx.x & 63;
    int gwave = (blockIdx.x * blockDim.x + threadIdx.x) >> 6;
    int nwav  = (gridDim.x * blockDim.x) >> 6;
    for (int ed = gwave; ed < e; ed += nwav) {
        int s = src[ed], d = dst[ed];
        float norm = dis[s] * dis[d];
        float v = h[(size_t)s * 64 + lane] * norm;
        atomicAdd(&agg[(size_t)d * 64 + lane], v);
    }
}

// out[i][0..3] = relu(agg[i]) @ Wfc + bfc ; wave per row, shuffle reduction
__global__ void k_final(const float* __restrict__ agg, const float* __restrict__ Wfc,
                        const float* __restrict__ bfc, float* __restrict__ out, int n) {
    int lane  = threadIdx.x & 63;
    int gwave = (blockIdx.x * blockDim.x + threadIdx.x) >> 6;
    int nwav  = (gridDim.x * blockDim.x) >> 6;
    float4 w = ((const float4*)Wfc)[lane];  // Wfc[lane][0..3]
    for (int row = gwave; row < n; row += nwav) {
        float a = fmaxf(agg[(size_t)row * 64 + lane], 0.f);
        float p0 = a * w.x, p1 = a * w.y, p2 = a * w.z, p3 = a * w.w;
        #pragma unroll
        for (int off = 32; off > 0; off >>= 1) {
            p0 += __shfl_down(p0, off);
            p1 += __shfl_down(p1, off);
            p2 += __shfl_down(p2, off);
            p3 += __shfl_down(p3, off);
        }
        if (lane == 0) {
            float4 o = { p0 + bfc[0], p1 + bfc[1], p2 + bfc[2], p3 + bfc[3] };
            ((float4*)out)[row] = o;
        }
    }
}

extern "C" void kernel_launch(void* const* d_in, const int* in_sizes, int n_in,
                              void* d_out, int out_size, void* d_ws, size_t ws_size,
                              hipStream_t stream) {
    const float* x   = (const float*)d_in[0];
    const int*   ei  = (const int*)d_in[1];
    const float* W1  = (const float*)d_in[2];
    const float* b1  = (const float*)d_in[3];
    const float* W2  = (const float*)d_in[4];
    const float* b2  = (const float*)d_in[5];
    const float* Wfc = (const float*)d_in[6];
    const float* bfc = (const float*)d_in[7];
    float* out = (float*)d_out;

    int n = in_sizes[0] / 128;   // 100000
    int e = in_sizes[1] / 2;     // 1600000
    const int* src = ei;
    const int* dst = ei + e;

    char* ws = (char*)d_ws;
    float* dis  = (float*)ws;                                     // n floats
    size_t off  = (((size_t)n * 4) + 255) & ~(size_t)255;
    float* bufA = (float*)(ws + off);                             // n*64
    float* bufB = bufA + (size_t)n * 64;                          // n*64

    int nb = (n + 255) / 256;
    int eb = (e + 255) / 256;
    int hb = (n * 64 + 255) / 256;

    // degree -> dis = rsqrt(deg)
    k_deg_init<<<nb, 256, 0, stream>>>(dis, n);
    k_deg_count<<<eb, 256, 0, stream>>>(dst, e, dis);
    k_rsqrt<<<nb, 256, 0, stream>>>(dis, n);

    // layer 1
    k_gemm<128, false><<<2048, 256, 0, stream>>>(x, W1, bufA, n);
    k_init<<<hb, 256, 0, stream>>>(bufA, dis, b1, bufB, n);
    k_scatter<<<4096, 256, 0, stream>>>(src, dst, dis, bufA, bufB, e);

    // layer 2 (relu fused into GEMM2 input read)
    k_gemm<64, true><<<2048, 256, 0, stream>>>(bufB, W2, bufA, n);
    k_init<<<hb, 256, 0, stream>>>(bufA, dis, b2, bufB, n);
    k_scatter<<<4096, 256, 0, stream>>>(src, dst, dis, bufA, bufB, e);

    // final projection
    k_final<<<(n + 3) / 4, 256, 0, stream>>>(bufB, Wfc, bfc, out, n);
}

// Round 2
// 736.811 us; speedup vs baseline: 1.6069x; 1.6069x over previous
//
#include <hip/hip_runtime.h>

// GCN via CSR gather (no fp32 atomics in hot path):
//   counts = hist(dst); dis = rsqrt(counts+1)
//   CSR: offsets = exscan(counts); csr[dst-bucket] = src
//   h1' = (x@W1)*dis ; a1 = relu(b1 + dis*(h1'[d] + sum_{e->d} h1'[src]))
//   h2' = (a1@W2)*dis; a2 = relu(b2 + dis*(h2'[d] + sum h2'[src]))
//   out = a2@Wfc + bfc

#define SCAN_B 256

__global__ void k_zero_i(int* p, int n) {
    int i = blockIdx.x * blockDim.x + threadIdx.x;
    if (i < n) p[i] = 0;
}

__global__ void k_hist(const int* __restrict__ dst, int e, int* counts) {
    int i = blockIdx.x * blockDim.x + threadIdx.x;
    if (i < e) atomicAdd(&counts[dst[i]], 1);
}

__global__ void k_dis(const int* __restrict__ counts, float* __restrict__ dis, int n) {
    int i = blockIdx.x * blockDim.x + threadIdx.x;
    if (i < n) dis[i] = rsqrtf((float)(counts[i] + 1));  // +1 self-loop
}

// exclusive scan, 3 phases
__global__ void k_scan1(const int* __restrict__ in, int* __restrict__ out,
                        int* __restrict__ bsum, int n) {
    __shared__ int tmp[SCAN_B];
    int gid = blockIdx.x * SCAN_B + threadIdx.x;
    int v = (gid < n) ? in[gid] : 0;
    tmp[threadIdx.x] = v;
    __syncthreads();
    for (int o = 1; o < SCAN_B; o <<= 1) {
        int t = (threadIdx.x >= o) ? tmp[threadIdx.x - o] : 0;
        __syncthreads();
        tmp[threadIdx.x] += t;
        __syncthreads();
    }
    int inc = tmp[threadIdx.x];
    if (gid < n) out[gid] = inc - v;               // exclusive
    if (threadIdx.x == SCAN_B - 1) bsum[blockIdx.x] = inc;
}

__global__ void k_scan2(int* bsum, int nb) {       // single block, nb <= 1024
    __shared__ int tmp[1024];
    int v = (threadIdx.x < nb) ? bsum[threadIdx.x] : 0;
    tmp[threadIdx.x] = v;
    __syncthreads();
    for (int o = 1; o < 1024; o <<= 1) {
        int t = (threadIdx.x >= o) ? tmp[threadIdx.x - o] : 0;
        __syncthreads();
        tmp[threadIdx.x] += t;
        __syncthreads();
    }
    if (threadIdx.x < nb) bsum[threadIdx.x] = tmp[threadIdx.x] - v;  // exclusive
}

__global__ void k_scan3(int* __restrict__ out, int* __restrict__ cursor,
                        const int* __restrict__ bsum, int n) {
    int gid = blockIdx.x * SCAN_B + threadIdx.x;
    if (gid < n) {
        int o = out[gid] + bsum[blockIdx.x];
        out[gid] = o;
        cursor[gid] = o;
    }
}

__global__ void k_fill(const int* __restrict__ src, const int* __restrict__ dst,
                       int e, int* cursor, int* __restrict__ csr) {
    int i = blockIdx.x * blockDim.x + threadIdx.x;
    if (i < e) {
        int pos = atomicAdd(&cursor[dst[i]], 1);
        csr[pos] = src[i];
    }
}

// Wave-per-row GEMM: X [n,K] @ W [K,64] -> H[row][lane] = acc * dis[row]
template<int K>
__global__ void k_gemm(const float* __restrict__ X, const float* __restrict__ W,
                       const float* __restrict__ dis, float* __restrict__ H, int n) {
    __shared__ float ws[K * 64];
    for (int idx = threadIdx.x; idx < K * 64; idx += blockDim.x) ws[idx] = W[idx];
    __syncthreads();

    int lane  = threadIdx.x & 63;
    int wave  = threadIdx.x >> 6;
    int wpb   = blockDim.x >> 6;
    int gwave = blockIdx.x * wpb + wave;
    int nwav  = gridDim.x * wpb;

    for (int row = gwave; row < n; row += nwav) {
        const float* xr = X + (size_t)row * K;
        float acc = 0.f;
        if (K == 128) {
            float2 xv = ((const float2*)xr)[lane];
            #pragma unroll 8
            for (int kk = 0; kk < 64; ++kk) {
                acc += __shfl(xv.x, kk) * ws[(2 * kk) * 64 + lane];
                acc += __shfl(xv.y, kk) * ws[(2 * kk + 1) * 64 + lane];
            }
        } else {
            float xv = xr[lane];
            #pragma unroll 8
            for (int kk = 0; kk < 64; ++kk) {
                acc += __shfl(xv, kk) * ws[kk * 64 + lane];
            }
        }
        H[(size_t)row * 64 + lane] = acc * dis[row];
    }
}

// Wave per node: 4 edges x 16 lanes x float4. out = relu(b + dis[d]*(self+sum))
__global__ void k_gather(const float* __restrict__ hp, const int* __restrict__ csr,
                         const int* __restrict__ off, const int* __restrict__ cnt,
                         const float* __restrict__ dis, const float* __restrict__ b,
                         float* __restrict__ outb, int n) {
    int lane = threadIdx.x & 63;
    int wid  = (blockIdx.x * blockDim.x + threadIdx.x) >> 6;
    if (wid >= n) return;
    int d    = wid;
    int esub = lane >> 4;          // 0..3: which edge of the group of 4
    int c4   = (lane & 15) * 4;    // channel base for this lane

    float4 acc = make_float4(0.f, 0.f, 0.f, 0.f);
    if (esub == 0)                 // self-loop term h'[d]
        acc = *(const float4*)(hp + (size_t)d * 64 + c4);

    int start = off[d], num = cnt[d];
    for (int j = 0; j < num; j += 4) {
        int jj = j + esub;
        if (jj < num) {
            int s = csr[start + jj];
            float4 v = *(const float4*)(hp + (size_t)s * 64 + c4);
            acc.x += v.x; acc.y += v.y; acc.z += v.z; acc.w += v.w;
        }
    }
    // reduce across the 4 edge-subgroups (lanes differing in bits 4,5)
    #pragma unroll
    for (int o = 16; o <= 32; o <<= 1) {
        acc.x += __shfl_xor(acc.x, o);
        acc.y += __shfl_xor(acc.y, o);
        acc.z += __shfl_xor(acc.z, o);
        acc.w += __shfl_xor(acc.w, o);
    }
    if (esub == 0) {
        float dd = dis[d];
        float4 bb = *(const float4*)(b + c4);
        float4 o;
        o.x = fmaxf(bb.x + dd * acc.x, 0.f);
        o.y = fmaxf(bb.y + dd * acc.y, 0.f);
        o.z = fmaxf(bb.z + dd * acc.z, 0.f);
        o.w = fmaxf(bb.w + dd * acc.w, 0.f);
        *(float4*)(outb + (size_t)d * 64 + c4) = o;
    }
}

// out[i][0..3] = a2[i] @ Wfc + bfc (a2 already relu'd); wave/row shuffle reduce
__global__ void k_final(const float* __restrict__ agg, const float* __restrict__ Wfc,
                        const float* __restrict__ bfc, float* __restrict__ out, int n) {
    int lane  = threadIdx.x & 63;
    int gwave = (blockIdx.x * blockDim.x + threadIdx.x) >> 6;
    int nwav  = (gridDim.x * blockDim.x) >> 6;
    float4 w = ((const float4*)Wfc)[lane];
    for (int row = gwave; row < n; row += nwav) {
        float a = agg[(size_t)row * 64 + lane];
        float p0 = a * w.x, p1 = a * w.y, p2 = a * w.z, p3 = a * w.w;
        #pragma unroll
        for (int off = 32; off > 0; off >>= 1) {
            p0 += __shfl_down(p0, off);
            p1 += __shfl_down(p1, off);
            p2 += __shfl_down(p2, off);
            p3 += __shfl_down(p3, off);
        }
        if (lane == 0) {
            float4 o = { p0 + bfc[0], p1 + bfc[1], p2 + bfc[2], p3 + bfc[3] };
            ((float4*)out)[row] = o;
        }
    }
}

static inline size_t align256(size_t x) { return (x + 255) & ~(size_t)255; }

extern "C" void kernel_launch(void* const* d_in, const int* in_sizes, int n_in,
                              void* d_out, int out_size, void* d_ws, size_t ws_size,
                              hipStream_t stream) {
    const float* x   = (const float*)d_in[0];
    const int*   ei  = (const int*)d_in[1];
    const float* W1  = (const float*)d_in[2];
    const float* b1  = (const float*)d_in[3];
    const float* W2  = (const float*)d_in[4];
    const float* b2  = (const float*)d_in[5];
    const float* Wfc = (const float*)d_in[6];
    const float* bfc = (const float*)d_in[7];
    float* out = (float*)d_out;

    int n = in_sizes[0] / 128;   // 100000
    int e = in_sizes[1] / 2;     // 1600000
    const int* src = ei;
    const int* dst = ei + e;

    char* ws = (char*)d_ws;
    size_t p = 0;
    float* dis     = (float*)(ws + p); p = align256(p + (size_t)n * 4);
    int*   counts  = (int*)  (ws + p); p = align256(p + (size_t)n * 4);
    int*   offs    = (int*)  (ws + p); p = align256(p + (size_t)n * 4);
    int*   cursor  = (int*)  (ws + p); p = align256(p + (size_t)n * 4);
    int*   bsum    = (int*)  (ws + p); p = align256(p + 1024 * 4);
    int*   csr     = (int*)  (ws + p); p = align256(p + (size_t)e * 4);
    float* bufA    = (float*)(ws + p); p = align256(p + (size_t)n * 64 * 4);
    float* bufB    = (float*)(ws + p);

    int nb  = (n + 255) / 256;
    int eb  = (e + 255) / 256;
    int nsb = (n + SCAN_B - 1) / SCAN_B;   // 391 <= 1024

    // CSR build + degree
    k_zero_i<<<nb, 256, 0, stream>>>(counts, n);
    k_hist<<<eb, 256, 0, stream>>>(dst, e, counts);
    k_dis<<<nb, 256, 0, stream>>>(counts, dis, n);
    k_scan1<<<nsb, SCAN_B, 0, stream>>>(counts, offs, bsum, n);
    k_scan2<<<1, 1024, 0, stream>>>(bsum, nsb);
    k_scan3<<<nsb, SCAN_B, 0, stream>>>(offs, cursor, bsum, n);
    k_fill<<<eb, 256, 0, stream>>>(src, dst, e, cursor, csr);

    // layer 1
    k_gemm<128><<<2048, 256, 0, stream>>>(x, W1, dis, bufA, n);
    k_gather<<<(n * 64 + 255) / 256, 256, 0, stream>>>(bufA, csr, offs, counts, dis, b1, bufB, n);

    // layer 2
    k_gemm<64><<<2048, 256, 0, stream>>>(bufB, W2, dis, bufA, n);
    k_gather<<<(n * 64 + 255) / 256, 256, 0, stream>>>(bufA, csr, offs, counts, dis, b2, bufB, n);

    // final projection
    k_final<<<(n + 3) / 4, 256, 0, stream>>>(bufB, Wfc, bfc, out, n);
}

// Round 3
// 516.583 us; speedup vs baseline: 2.2919x; 1.4263x over previous
//
#include <hip/hip_runtime.h>

// GCN via CSR gather (no fp32 atomics in hot path):
//   counts = hist(dst); dis = rsqrt(counts+1)
//   CSR: offsets = exscan(counts); csr[dst-bucket] = src
//   h1' = (x@W1)*dis ; a1 = relu(b1 + dis*(h1'[d] + sum_{e->d} h1'[src]))
//   h2' = (a1@W2)*dis; a2 = relu(b2 + dis*(h2'[d] + sum h2'[src]))
//   out = a2@Wfc + bfc
// GEMMs: register-tiled (128 rows x 64 cols per block, 8x4 acc per thread),
// W in LDS, x-chunk transposed in LDS (stride 132 to keep float4 alignment
// and avoid transpose bank conflicts). 3 ds_read_b128 per 32 FMA.

#define SCAN_B 256

__global__ void k_zero_i(int* p, int n) {
    int i = blockIdx.x * blockDim.x + threadIdx.x;
    if (i < n) p[i] = 0;
}

__global__ void k_hist(const int* __restrict__ dst, int e, int* counts) {
    int i = blockIdx.x * blockDim.x + threadIdx.x;
    if (i < e) atomicAdd(&counts[dst[i]], 1);
}

__global__ void k_dis(const int* __restrict__ counts, float* __restrict__ dis, int n) {
    int i = blockIdx.x * blockDim.x + threadIdx.x;
    if (i < n) dis[i] = rsqrtf((float)(counts[i] + 1));  // +1 self-loop
}

// exclusive scan, 3 phases
__global__ void k_scan1(const int* __restrict__ in, int* __restrict__ out,
                        int* __restrict__ bsum, int n) {
    __shared__ int tmp[SCAN_B];
    int gid = blockIdx.x * SCAN_B + threadIdx.x;
    int v = (gid < n) ? in[gid] : 0;
    tmp[threadIdx.x] = v;
    __syncthreads();
    for (int o = 1; o < SCAN_B; o <<= 1) {
        int t = (threadIdx.x >= o) ? tmp[threadIdx.x - o] : 0;
        __syncthreads();
        tmp[threadIdx.x] += t;
        __syncthreads();
    }
    int inc = tmp[threadIdx.x];
    if (gid < n) out[gid] = inc - v;               // exclusive
    if (threadIdx.x == SCAN_B - 1) bsum[blockIdx.x] = inc;
}

__global__ void k_scan2(int* bsum, int nb) {       // single block, nb <= 1024
    __shared__ int tmp[1024];
    int v = (threadIdx.x < nb) ? bsum[threadIdx.x] : 0;
    tmp[threadIdx.x] = v;
    __syncthreads();
    for (int o = 1; o < 1024; o <<= 1) {
        int t = (threadIdx.x >= o) ? tmp[threadIdx.x - o] : 0;
        __syncthreads();
        tmp[threadIdx.x] += t;
        __syncthreads();
    }
    if (threadIdx.x < nb) bsum[threadIdx.x] = tmp[threadIdx.x] - v;  // exclusive
}

__global__ void k_scan3(int* __restrict__ out, int* __restrict__ cursor,
                        const int* __restrict__ bsum, int n) {
    int gid = blockIdx.x * SCAN_B + threadIdx.x;
    if (gid < n) {
        int o = out[gid] + bsum[blockIdx.x];
        out[gid] = o;
        cursor[gid] = o;
    }
}

__global__ void k_fill(const int* __restrict__ src, const int* __restrict__ dst,
                       int e, int* cursor, int* __restrict__ csr) {
    int i = blockIdx.x * blockDim.x + threadIdx.x;
    if (i < e) {
        int pos = atomicAdd(&cursor[dst[i]], 1);
        csr[pos] = src[i];
    }
}

// Register-tiled GEMM: X[n,K] @ W[K,64] -> H[row][col] = acc * dis[row]
// Block: 128 rows x 64 cols, 256 threads, each 8 rows x 4 cols.
template<int K>
__global__ __launch_bounds__(256) void k_gemm_t(const float* __restrict__ X,
                                                const float* __restrict__ W,
                                                const float* __restrict__ dis,
                                                float* __restrict__ H, int n) {
    constexpr int BM = 128, CK = 32, XS = BM + 4;  // XS=132: pad, 16B-aligned
    __shared__ float ws[K * 64];
    __shared__ float xT[CK * XS];

    int t = threadIdx.x;
    for (int i = t; i < K * 16; i += 256)
        ((float4*)ws)[i] = ((const float4*)W)[i];

    int row0 = blockIdx.x * BM;
    int col4 = (t & 15) * 4;
    int row8 = (t >> 4) * 8;
    int kq   = t & 7;        // which float4 of the 32-k chunk
    int rr   = t >> 3;       // 0..31

    float acc[8][4] = {};

    for (int kc = 0; kc < K; kc += CK) {
        __syncthreads();     // ws ready (1st iter) / prev-chunk reads done
        #pragma unroll
        for (int p = 0; p < 4; ++p) {
            int row  = p * 32 + rr;
            int grow = row0 + row;
            float4 v = make_float4(0.f, 0.f, 0.f, 0.f);
            if (grow < n)
                v = *(const float4*)(X + (size_t)grow * K + kc + kq * 4);
            xT[(kq * 4 + 0) * XS + row] = v.x;
            xT[(kq * 4 + 1) * XS + row] = v.y;
            xT[(kq * 4 + 2) * XS + row] = v.z;
            xT[(kq * 4 + 3) * XS + row] = v.w;
        }
        __syncthreads();
        #pragma unroll
        for (int k = 0; k < CK; ++k) {
            float4 wv  = *(const float4*)(ws + (kc + k) * 64 + col4);
            float4 xv0 = *(const float4*)(xT + k * XS + row8);
            float4 xv1 = *(const float4*)(xT + k * XS + row8 + 4);
            float xv[8] = { xv0.x, xv0.y, xv0.z, xv0.w,
                            xv1.x, xv1.y, xv1.z, xv1.w };
            float wf[4] = { wv.x, wv.y, wv.z, wv.w };
            #pragma unroll
            for (int i = 0; i < 8; ++i)
                #pragma unroll
                for (int j = 0; j < 4; ++j)
                    acc[i][j] += xv[i] * wf[j];
        }
    }

    #pragma unroll
    for (int i = 0; i < 8; ++i) {
        int grow = row0 + row8 + i;
        if (grow < n) {
            float d = dis[grow];
            float4 o = make_float4(acc[i][0] * d, acc[i][1] * d,
                                   acc[i][2] * d, acc[i][3] * d);
            *(float4*)(H + (size_t)grow * 64 + col4) = o;
        }
    }
}

// Wave per node: 4 edges x 16 lanes x float4. out = relu(b + dis[d]*(self+sum))
__global__ void k_gather(const float* __restrict__ hp, const int* __restrict__ csr,
                         const int* __restrict__ off, const int* __restrict__ cnt,
                         const float* __restrict__ dis, const float* __restrict__ b,
                         float* __restrict__ outb, int n) {
    int lane = threadIdx.x & 63;
    int wid  = (blockIdx.x * blockDim.x + threadIdx.x) >> 6;
    if (wid >= n) return;
    int d    = wid;
    int esub = lane >> 4;          // 0..3: which edge of the group of 4
    int c4   = (lane & 15) * 4;    // channel base for this lane

    float4 acc = make_float4(0.f, 0.f, 0.f, 0.f);
    if (esub == 0)                 // self-loop term h'[d]
        acc = *(const float4*)(hp + (size_t)d * 64 + c4);

    int start = off[d], num = cnt[d];
    for (int j = 0; j < num; j += 4) {
        int jj = j + esub;
        if (jj < num) {
            int s = csr[start + jj];
            float4 v = *(const float4*)(hp + (size_t)s * 64 + c4);
            acc.x += v.x; acc.y += v.y; acc.z += v.z; acc.w += v.w;
        }
    }
    // reduce across the 4 edge-subgroups (lanes differing in bits 4,5)
    #pragma unroll
    for (int o = 16; o <= 32; o <<= 1) {
        acc.x += __shfl_xor(acc.x, o);
        acc.y += __shfl_xor(acc.y, o);
        acc.z += __shfl_xor(acc.z, o);
        acc.w += __shfl_xor(acc.w, o);
    }
    if (esub == 0) {
        float dd = dis[d];
        float4 bb = *(const float4*)(b + c4);
        float4 o;
        o.x = fmaxf(bb.x + dd * acc.x, 0.f);
        o.y = fmaxf(bb.y + dd * acc.y, 0.f);
        o.z = fmaxf(bb.z + dd * acc.z, 0.f);
        o.w = fmaxf(bb.w + dd * acc.w, 0.f);
        *(float4*)(outb + (size_t)d * 64 + c4) = o;
    }
}

// out[i][0..3] = a2[i] @ Wfc + bfc (a2 already relu'd); wave/row shuffle reduce
__global__ void k_final(const float* __restrict__ agg, const float* __restrict__ Wfc,
                        const float* __restrict__ bfc, float* __restrict__ out, int n) {
    int lane  = threadIdx.x & 63;
    int gwave = (blockIdx.x * blockDim.x + threadIdx.x) >> 6;
    int nwav  = (gridDim.x * blockDim.x) >> 6;
    float4 w = ((const float4*)Wfc)[lane];
    for (int row = gwave; row < n; row += nwav) {
        float a = agg[(size_t)row * 64 + lane];
        float p0 = a * w.x, p1 = a * w.y, p2 = a * w.z, p3 = a * w.w;
        #pragma unroll
        for (int off = 32; off > 0; off >>= 1) {
            p0 += __shfl_down(p0, off);
            p1 += __shfl_down(p1, off);
            p2 += __shfl_down(p2, off);
            p3 += __shfl_down(p3, off);
        }
        if (lane == 0) {
            float4 o = { p0 + bfc[0], p1 + bfc[1], p2 + bfc[2], p3 + bfc[3] };
            ((float4*)out)[row] = o;
        }
    }
}

static inline size_t align256(size_t x) { return (x + 255) & ~(size_t)255; }

extern "C" void kernel_launch(void* const* d_in, const int* in_sizes, int n_in,
                              void* d_out, int out_size, void* d_ws, size_t ws_size,
                              hipStream_t stream) {
    const float* x   = (const float*)d_in[0];
    const int*   ei  = (const int*)d_in[1];
    const float* W1  = (const float*)d_in[2];
    const float* b1  = (const float*)d_in[3];
    const float* W2  = (const float*)d_in[4];
    const float* b2  = (const float*)d_in[5];
    const float* Wfc = (const float*)d_in[6];
    const float* bfc = (const float*)d_in[7];
    float* out = (float*)d_out;

    int n = in_sizes[0] / 128;   // 100000
    int e = in_sizes[1] / 2;     // 1600000
    const int* src = ei;
    const int* dst = ei + e;

    char* ws = (char*)d_ws;
    size_t p = 0;
    float* dis     = (float*)(ws + p); p = align256(p + (size_t)n * 4);
    int*   counts  = (int*)  (ws + p); p = align256(p + (size_t)n * 4);
    int*   offs    = (int*)  (ws + p); p = align256(p + (size_t)n * 4);
    int*   cursor  = (int*)  (ws + p); p = align256(p + (size_t)n * 4);
    int*   bsum    = (int*)  (ws + p); p = align256(p + 1024 * 4);
    int*   csr     = (int*)  (ws + p); p = align256(p + (size_t)e * 4);
    float* bufA    = (float*)(ws + p); p = align256(p + (size_t)n * 64 * 4);
    float* bufB    = (float*)(ws + p);

    int nb  = (n + 255) / 256;
    int eb  = (e + 255) / 256;
    int nsb = (n + SCAN_B - 1) / SCAN_B;   // 391 <= 1024
    int gb  = (n + 127) / 128;             // gemm tiles

    // CSR build + degree
    k_zero_i<<<nb, 256, 0, stream>>>(counts, n);
    k_hist<<<eb, 256, 0, stream>>>(dst, e, counts);
    k_dis<<<nb, 256, 0, stream>>>(counts, dis, n);
    k_scan1<<<nsb, SCAN_B, 0, stream>>>(counts, offs, bsum, n);
    k_scan2<<<1, 1024, 0, stream>>>(bsum, nsb);
    k_scan3<<<nsb, SCAN_B, 0, stream>>>(offs, cursor, bsum, n);
    k_fill<<<eb, 256, 0, stream>>>(src, dst, e, cursor, csr);

    // layer 1
    k_gemm_t<128><<<gb, 256, 0, stream>>>(x, W1, dis, bufA, n);
    k_gather<<<(n * 64 + 255) / 256, 256, 0, stream>>>(bufA, csr, offs, counts, dis, b1, bufB, n);

    // layer 2
    k_gemm_t<64><<<gb, 256, 0, stream>>>(bufB, W2, dis, bufA, n);
    k_gather<<<(n * 64 + 255) / 256, 256, 0, stream>>>(bufA, csr, offs, counts, dis, b2, bufB, n);

    // final projection
    k_final<<<(n + 3) / 4, 256, 0, stream>>>(bufB, Wfc, bfc, out, n);
}

// Round 4
// 341.465 us; speedup vs baseline: 3.4673x; 1.5128x over previous
//
#include <hip/hip_runtime.h>

// GCN via two-level multisplit CSR build + gather (no fp32 atomics anywhere):
//   bucket = dst>>8 (391 buckets of 256 nodes)
//   k_bcount: global bucket histogram (LDS-aggregated)
//   k_bscan : exclusive scan of bucket counts -> bbase, bcur
//   k_bin   : partition edges into bucket-contiguous (src,dst) pairs;
//             per-block LDS ranks, ONE global atomic per (block,bucket)
//   k_bucket: per-bucket local counting sort -> csr, offs, cnt, dis (coalesced)
//   h1' = (x@W1)*dis ; a1 = relu(b1 + dis*(h1'[d] + sum_{e->d} h1'[src]))
//   h2' = (a1@W2)*dis; out = relu(b2 + dis*(...)) @ Wfc + bfc  (final fused)
// GEMMs: register-tiled 128x64 per block, 8x4 acc per thread.

__global__ void k_zero_i(int* p, int n) {
    int i = blockIdx.x * blockDim.x + threadIdx.x;
    if (i < n) p[i] = 0;
}

__global__ __launch_bounds__(256) void k_bcount(const int* __restrict__ dst, int e,
                                                int* __restrict__ bcnt) {
    __shared__ int lh[512];
    for (int i = threadIdx.x; i < 512; i += 256) lh[i] = 0;
    __syncthreads();
    for (int i = blockIdx.x * blockDim.x + threadIdx.x; i < e;
         i += gridDim.x * blockDim.x)
        atomicAdd(&lh[dst[i] >> 8], 1);
    __syncthreads();
    for (int i = threadIdx.x; i < 512; i += 256)
        if (lh[i]) atomicAdd(&bcnt[i], lh[i]);
}

__global__ __launch_bounds__(512) void k_bscan(const int* __restrict__ bcnt,
                                               int* __restrict__ bbase,
                                               int* __restrict__ bcur) {
    __shared__ int tmp[512];
    int t = threadIdx.x;
    int v = bcnt[t];
    tmp[t] = v;
    __syncthreads();
    for (int o = 1; o < 512; o <<= 1) {
        int x = (t >= o) ? tmp[t - o] : 0;
        __syncthreads();
        tmp[t] += x;
        __syncthreads();
    }
    int ex = tmp[t] - v;
    bbase[t] = ex;
    bcur[t] = ex;
}

// Partition edges into bucket-contiguous runs. Per block: LDS hist -> one
// global atomic per bucket -> LDS-ranked scatter of int2(src,dst).
__global__ __launch_bounds__(256) void k_bin(const int* __restrict__ src,
                                             const int* __restrict__ dst, int e,
                                             int* bcur, int2* __restrict__ binned) {
    __shared__ int lh[512], lbase[512], lr[512];
    int t = threadIdx.x;
    for (int i = t; i < 512; i += 256) { lh[i] = 0; lr[i] = 0; }
    __syncthreads();
    int chunk = (e + gridDim.x - 1) / gridDim.x;
    int lo = blockIdx.x * chunk;
    int hi = min(e, lo + chunk);
    for (int i = lo + t; i < hi; i += 256)
        atomicAdd(&lh[dst[i] >> 8], 1);
    __syncthreads();
    for (int i = t; i < 512; i += 256)
        lbase[i] = lh[i] ? atomicAdd(&bcur[i], lh[i]) : 0;
    __syncthreads();
    for (int i = lo + t; i < hi; i += 256) {
        int d = dst[i];
        int b = d >> 8;
        int r = atomicAdd(&lr[b], 1);
        binned[lbase[b] + r] = make_int2(src[i], d);
    }
}

// One block per bucket: counting sort of <=~4500 edges over 256 local nodes.
// Emits csr (bucket-local scatter, L2-resident), offs/cnt/dis coalesced.
__global__ __launch_bounds__(256) void k_bucket(const int2* __restrict__ binned,
                                                const int* __restrict__ bbase,
                                                const int* __restrict__ bcnt,
                                                int n, int* __restrict__ offs,
                                                int* __restrict__ cnt,
                                                float* __restrict__ dis,
                                                int* __restrict__ csr) {
    __shared__ int nh[256], nsc[256], nr[256];
    int b = blockIdx.x, t = threadIdx.x;
    int node0 = b << 8;
    int ebase = bbase[b], ecnt = bcnt[b];
    nh[t] = 0; nr[t] = 0;
    __syncthreads();
    for (int j = t; j < ecnt; j += 256)
        atomicAdd(&nh[binned[ebase + j].y & 255], 1);
    __syncthreads();
    int v = nh[t];
    nsc[t] = v;
    __syncthreads();
    for (int o = 1; o < 256; o <<= 1) {
        int x = (t >= o) ? nsc[t - o] : 0;
        __syncthreads();
        nsc[t] += x;
        __syncthreads();
    }
    int ex = nsc[t] - v;
    int d = node0 + t;
    if (d < n) {
        offs[d] = ebase + ex;
        cnt[d]  = v;
        dis[d]  = rsqrtf((float)(v + 1));   // +1 self-loop
    }
    nsc[t] = ex;
    __syncthreads();
    for (int j = t; j < ecnt; j += 256) {
        int2 ed = binned[ebase + j];
        int ld = ed.y & 255;
        int r = atomicAdd(&nr[ld], 1);
        csr[ebase + nsc[ld] + r] = ed.x;
    }
}

// Register-tiled GEMM: X[n,K] @ W[K,64] -> H[row][col] = acc * dis[row]
// Block: 128 rows x 64 cols, 256 threads, each 8 rows x 4 cols.
template<int K>
__global__ __launch_bounds__(256) void k_gemm_t(const float* __restrict__ X,
                                                const float* __restrict__ W,
                                                const float* __restrict__ dis,
                                                float* __restrict__ H, int n) {
    constexpr int BM = 128, CK = 32, XS = BM + 4;
    __shared__ float ws[K * 64];
    __shared__ float xT[CK * XS];

    int t = threadIdx.x;
    for (int i = t; i < K * 16; i += 256)
        ((float4*)ws)[i] = ((const float4*)W)[i];

    int row0 = blockIdx.x * BM;
    int col4 = (t & 15) * 4;
    int row8 = (t >> 4) * 8;
    int kq   = t & 7;
    int rr   = t >> 3;

    float acc[8][4] = {};

    for (int kc = 0; kc < K; kc += CK) {
        __syncthreads();
        #pragma unroll
        for (int p = 0; p < 4; ++p) {
            int row  = p * 32 + rr;
            int grow = row0 + row;
            float4 v = make_float4(0.f, 0.f, 0.f, 0.f);
            if (grow < n)
                v = *(const float4*)(X + (size_t)grow * K + kc + kq * 4);
            xT[(kq * 4 + 0) * XS + row] = v.x;
            xT[(kq * 4 + 1) * XS + row] = v.y;
            xT[(kq * 4 + 2) * XS + row] = v.z;
            xT[(kq * 4 + 3) * XS + row] = v.w;
        }
        __syncthreads();
        #pragma unroll
        for (int k = 0; k < CK; ++k) {
            float4 wv  = *(const float4*)(ws + (kc + k) * 64 + col4);
            float4 xv0 = *(const float4*)(xT + k * XS + row8);
            float4 xv1 = *(const float4*)(xT + k * XS + row8 + 4);
            float xv[8] = { xv0.x, xv0.y, xv0.z, xv0.w,
                            xv1.x, xv1.y, xv1.z, xv1.w };
            float wf[4] = { wv.x, wv.y, wv.z, wv.w };
            #pragma unroll
            for (int i = 0; i < 8; ++i)
                #pragma unroll
                for (int j = 0; j < 4; ++j)
                    acc[i][j] += xv[i] * wf[j];
        }
    }

    #pragma unroll
    for (int i = 0; i < 8; ++i) {
        int grow = row0 + row8 + i;
        if (grow < n) {
            float d = dis[grow];
            float4 o = make_float4(acc[i][0] * d, acc[i][1] * d,
                                   acc[i][2] * d, acc[i][3] * d);
            *(float4*)(H + (size_t)grow * 64 + col4) = o;
        }
    }
}

// Wave per node: 4 edges x 16 lanes x float4, unrolled to 8 edges in flight.
// a = relu(b + dis[d]*(self + sum)). If FUSE: out[d] = a @ Wfc + bfc (float4).
template<bool FUSE>
__global__ __launch_bounds__(256) void k_gather(const float* __restrict__ hp,
                                                const int* __restrict__ csr,
                                                const int* __restrict__ off,
                                                const int* __restrict__ cnt,
                                                const float* __restrict__ dis,
                                                const float* __restrict__ bias,
                                                float* __restrict__ outb,
                                                const float* __restrict__ Wfc,
                                                const float* __restrict__ bfc,
                                                int n) {
    int lane = threadIdx.x & 63;
    int wid  = (blockIdx.x * blockDim.x + threadIdx.x) >> 6;
    if (wid >= n) return;
    int d    = wid;
    int esub = lane >> 4;
    int c4   = (lane & 15) * 4;

    float4 a0 = make_float4(0.f, 0.f, 0.f, 0.f);
    float4 a1 = make_float4(0.f, 0.f, 0.f, 0.f);
    if (esub == 0)
        a0 = *(const float4*)(hp + (size_t)d * 64 + c4);

    int start = off[d], num = cnt[d];
    int j = 0;
    for (; j + 8 <= num; j += 8) {
        int s0 = csr[start + j + esub];
        int s1 = csr[start + j + 4 + esub];
        float4 v0 = *(const float4*)(hp + (size_t)s0 * 64 + c4);
        float4 v1 = *(const float4*)(hp + (size_t)s1 * 64 + c4);
        a0.x += v0.x; a0.y += v0.y; a0.z += v0.z; a0.w += v0.w;
        a1.x += v1.x; a1.y += v1.y; a1.z += v1.z; a1.w += v1.w;
    }
    for (; j < num; j += 4) {
        int jj = j + esub;
        if (jj < num) {
            int s = csr[start + jj];
            float4 v = *(const float4*)(hp + (size_t)s * 64 + c4);
            a0.x += v.x; a0.y += v.y; a0.z += v.z; a0.w += v.w;
        }
    }
    a0.x += a1.x; a0.y += a1.y; a0.z += a1.z; a0.w += a1.w;
    #pragma unroll
    for (int o = 16; o <= 32; o <<= 1) {
        a0.x += __shfl_xor(a0.x, o);
        a0.y += __shfl_xor(a0.y, o);
        a0.z += __shfl_xor(a0.z, o);
        a0.w += __shfl_xor(a0.w, o);
    }
    float dd = dis[d];
    float4 bb = *(const float4*)(bias + c4);
    float4 o;
    o.x = fmaxf(bb.x + dd * a0.x, 0.f);
    o.y = fmaxf(bb.y + dd * a0.y, 0.f);
    o.z = fmaxf(bb.z + dd * a0.z, 0.f);
    o.w = fmaxf(bb.w + dd * a0.w, 0.f);
    if (!FUSE) {
        if (esub == 0)
            *(float4*)(outb + (size_t)d * 64 + c4) = o;
    } else {
        // every lane holds the full sums for its channel group; dot with Wfc
        const float4* W4 = (const float4*)Wfc;   // row r -> Wfc[r][0..3]
        float4 w0 = W4[c4 + 0], w1 = W4[c4 + 1], w2 = W4[c4 + 2], w3 = W4[c4 + 3];
        float4 p;
        p.x = o.x * w0.x + o.y * w1.x + o.z * w2.x + o.w * w3.x;
        p.y = o.x * w0.y + o.y * w1.y + o.z * w2.y + o.w * w3.y;
        p.z = o.x * w0.z + o.y * w1.z + o.z * w2.z + o.w * w3.z;
        p.w = o.x * w0.w + o.y * w1.w + o.z * w2.w + o.w * w3.w;
        #pragma unroll
        for (int q = 1; q <= 8; q <<= 1) {
            p.x += __shfl_xor(p.x, q);
            p.y += __shfl_xor(p.y, q);
            p.z += __shfl_xor(p.z, q);
            p.w += __shfl_xor(p.w, q);
        }
        if (lane == 0) {
            float4 bf = *(const float4*)bfc;
            float4 r = make_float4(p.x + bf.x, p.y + bf.y, p.z + bf.z, p.w + bf.w);
            ((float4*)outb)[d] = r;
        }
    }
}

static inline size_t align256(size_t x) { return (x + 255) & ~(size_t)255; }

extern "C" void kernel_launch(void* const* d_in, const int* in_sizes, int n_in,
                              void* d_out, int out_size, void* d_ws, size_t ws_size,
                              hipStream_t stream) {
    const float* x   = (const float*)d_in[0];
    const int*   ei  = (const int*)d_in[1];
    const float* W1  = (const float*)d_in[2];
    const float* b1  = (const float*)d_in[3];
    const float* W2  = (const float*)d_in[4];
    const float* b2  = (const float*)d_in[5];
    const float* Wfc = (const float*)d_in[6];
    const float* bfc = (const float*)d_in[7];
    float* out = (float*)d_out;

    int n = in_sizes[0] / 128;   // 100000
    int e = in_sizes[1] / 2;     // 1600000
    const int* src = ei;
    const int* dst = ei + e;

    char* ws = (char*)d_ws;
    size_t p = 0;
    float* dis    = (float*)(ws + p); p = align256(p + (size_t)n * 4);
    int*   counts = (int*)  (ws + p); p = align256(p + (size_t)n * 4);
    int*   offs   = (int*)  (ws + p); p = align256(p + (size_t)n * 4);
    int*   bcnt   = (int*)  (ws + p); p = align256(p + 512 * 4);
    int*   bbase  = (int*)  (ws + p); p = align256(p + 512 * 4);
    int*   bcur   = (int*)  (ws + p); p = align256(p + 512 * 4);
    int*   csr    = (int*)  (ws + p); p = align256(p + (size_t)e * 4);
    float* bufA   = (float*)(ws + p); p = align256(p + (size_t)n * 64 * 4);
    float* bufB   = (float*)(ws + p);
    int2*  binned = (int2*)bufB;     // alias: binned dead before bufB first write

    int gb = (n + 127) / 128;        // gemm tiles
    int nbk = (n + 255) / 256;       // buckets = 391

    // CSR build (two-level multisplit) + deg/dis/offs
    k_zero_i<<<2, 256, 0, stream>>>(bcnt, 512);
    k_bcount<<<256, 256, 0, stream>>>(dst, e, bcnt);
    k_bscan<<<1, 512, 0, stream>>>(bcnt, bbase, bcur);
    k_bin<<<256, 256, 0, stream>>>(src, dst, e, bcur, binned);
    k_bucket<<<nbk, 256, 0, stream>>>(binned, bbase, bcnt, n, offs, counts, dis, csr);

    // layer 1
    k_gemm_t<128><<<gb, 256, 0, stream>>>(x, W1, dis, bufA, n);
    k_gather<false><<<(n * 64 + 255) / 256, 256, 0, stream>>>(
        bufA, csr, offs, counts, dis, b1, bufB, nullptr, nullptr, n);

    // layer 2 + fused final projection
    k_gemm_t<64><<<gb, 256, 0, stream>>>(bufB, W2, dis, bufA, n);
    k_gather<true><<<(n * 64 + 255) / 256, 256, 0, stream>>>(
        bufA, csr, offs, counts, dis, b2, out, Wfc, bfc, n);
}

// Round 6
// 326.372 us; speedup vs baseline: 3.6277x; 1.0462x over previous
//
#include <hip/hip_runtime.h>

// GCN via two-level multisplit CSR build + gather (no fp32 atomics anywhere):
//   bucket = dst>>8 (391 buckets of 256 nodes)
//   k_bcount: global bucket histogram (LDS-aggregated)
//   k_bscan : exclusive scan of bucket counts -> bbase, bcur
//   k_bin   : partition edges into bucket-contiguous packed u32 (src<<8|ldst)
//   k_bucket: per-bucket local counting sort -> csr, offs, cnt, dis (coalesced)
//   h1' = (x@W1)*dis ; a1 = relu(b1 + dis*(h1'[d] + sum_{e->d} h1'[src]))
//   h2' = (a1@W2)*dis; out = relu(b2 + dis*(...)) @ Wfc + bfc  (final fused)
// GEMMs: register-tiled 128x64, v2f accumulators to hit v_pk_fma_f32.
// Gather: per-node index prefetch -> shfl-broadcast indices, 16 rows in
// flight. NOTE: all __shfl calls are in wave-uniform control flow — a shfl
// inside a divergent branch reads inactive source lanes = undefined (this
// was the R5 correctness bug). Only loads/adds are predicated.

typedef float v2f __attribute__((ext_vector_type(2)));

__global__ void k_zero_i(int* p, int n) {
    int i = blockIdx.x * blockDim.x + threadIdx.x;
    if (i < n) p[i] = 0;
}

__global__ __launch_bounds__(256) void k_bcount(const int* __restrict__ dst, int e,
                                                int* __restrict__ bcnt) {
    __shared__ int lh[512];
    for (int i = threadIdx.x; i < 512; i += 256) lh[i] = 0;
    __syncthreads();
    for (int i = blockIdx.x * blockDim.x + threadIdx.x; i < e;
         i += gridDim.x * blockDim.x)
        atomicAdd(&lh[dst[i] >> 8], 1);
    __syncthreads();
    for (int i = threadIdx.x; i < 512; i += 256)
        if (lh[i]) atomicAdd(&bcnt[i], lh[i]);
}

__global__ __launch_bounds__(512) void k_bscan(const int* __restrict__ bcnt,
                                               int* __restrict__ bbase,
                                               int* __restrict__ bcur) {
    __shared__ int tmp[512];
    int t = threadIdx.x;
    int v = bcnt[t];
    tmp[t] = v;
    __syncthreads();
    for (int o = 1; o < 512; o <<= 1) {
        int x = (t >= o) ? tmp[t - o] : 0;
        __syncthreads();
        tmp[t] += x;
        __syncthreads();
    }
    int ex = tmp[t] - v;
    bbase[t] = ex;
    bcur[t] = ex;
}

// Partition edges into bucket-contiguous runs of packed u32 (src<<8 | ldst).
__global__ __launch_bounds__(256) void k_bin(const int* __restrict__ src,
                                             const int* __restrict__ dst, int e,
                                             int* bcur, unsigned* __restrict__ binned) {
    __shared__ int lh[512], lbase[512], lr[512];
    int t = threadIdx.x;
    for (int i = t; i < 512; i += 256) { lh[i] = 0; lr[i] = 0; }
    __syncthreads();
    int chunk = (e + gridDim.x - 1) / gridDim.x;
    int lo = blockIdx.x * chunk;
    int hi = min(e, lo + chunk);
    for (int i = lo + t; i < hi; i += 256)
        atomicAdd(&lh[dst[i] >> 8], 1);
    __syncthreads();
    for (int i = t; i < 512; i += 256)
        lbase[i] = lh[i] ? atomicAdd(&bcur[i], lh[i]) : 0;
    __syncthreads();
    for (int i = lo + t; i < hi; i += 256) {
        int d = dst[i];
        int b = d >> 8;
        int r = atomicAdd(&lr[b], 1);
        binned[lbase[b] + r] = ((unsigned)src[i] << 8) | (unsigned)(d & 255);
    }
}

// One block per bucket: counting sort of <=~4500 edges over 256 local nodes.
__global__ __launch_bounds__(256) void k_bucket(const unsigned* __restrict__ binned,
                                                const int* __restrict__ bbase,
                                                const int* __restrict__ bcnt,
                                                int n, int* __restrict__ offs,
                                                int* __restrict__ cnt,
                                                float* __restrict__ dis,
                                                int* __restrict__ csr) {
    __shared__ int nh[256], nsc[256], nr[256];
    int b = blockIdx.x, t = threadIdx.x;
    int node0 = b << 8;
    int ebase = bbase[b], ecnt = bcnt[b];
    nh[t] = 0; nr[t] = 0;
    __syncthreads();
    for (int j = t; j < ecnt; j += 256)
        atomicAdd(&nh[binned[ebase + j] & 255u], 1);
    __syncthreads();
    int v = nh[t];
    nsc[t] = v;
    __syncthreads();
    for (int o = 1; o < 256; o <<= 1) {
        int x = (t >= o) ? nsc[t - o] : 0;
        __syncthreads();
        nsc[t] += x;
        __syncthreads();
    }
    int ex = nsc[t] - v;
    int d = node0 + t;
    if (d < n) {
        offs[d] = ebase + ex;
        cnt[d]  = v;
        dis[d]  = rsqrtf((float)(v + 1));   // +1 self-loop
    }
    nsc[t] = ex;
    __syncthreads();
    for (int j = t; j < ecnt; j += 256) {
        unsigned ed = binned[ebase + j];
        int ld = ed & 255u;
        int r = atomicAdd(&nr[ld], 1);
        csr[ebase + nsc[ld] + r] = (int)(ed >> 8);
    }
}

// Register-tiled GEMM: X[n,K] @ W[K,64] -> H[row][col] = acc * dis[row]
// Block: 128 rows x 64 cols, 256 threads, each 8 rows x 4 cols (v2f pairs).
template<int K>
__global__ __launch_bounds__(256) void k_gemm_t(const float* __restrict__ X,
                                                const float* __restrict__ W,
                                                const float* __restrict__ dis,
                                                float* __restrict__ H, int n) {
    constexpr int BM = 128, CK = 32, XS = BM + 4;
    __shared__ float ws[K * 64];
    __shared__ float xT[CK * XS];

    int t = threadIdx.x;
    for (int i = t; i < K * 16; i += 256)
        ((float4*)ws)[i] = ((const float4*)W)[i];

    int row0 = blockIdx.x * BM;
    int col4 = (t & 15) * 4;
    int row8 = (t >> 4) * 8;
    int kq   = t & 7;
    int rr   = t >> 3;

    v2f acc[8][2] = {};

    for (int kc = 0; kc < K; kc += CK) {
        __syncthreads();
        #pragma unroll
        for (int p = 0; p < 4; ++p) {
            int row  = p * 32 + rr;
            int grow = row0 + row;
            float4 v = make_float4(0.f, 0.f, 0.f, 0.f);
            if (grow < n)
                v = *(const float4*)(X + (size_t)grow * K + kc + kq * 4);
            xT[(kq * 4 + 0) * XS + row] = v.x;
            xT[(kq * 4 + 1) * XS + row] = v.y;
            xT[(kq * 4 + 2) * XS + row] = v.z;
            xT[(kq * 4 + 3) * XS + row] = v.w;
        }
        __syncthreads();
        #pragma unroll
        for (int k = 0; k < CK; ++k) {
            float4 wv  = *(const float4*)(ws + (kc + k) * 64 + col4);
            float4 xv0 = *(const float4*)(xT + k * XS + row8);
            float4 xv1 = *(const float4*)(xT + k * XS + row8 + 4);
            v2f w0 = { wv.x, wv.y };
            v2f w1 = { wv.z, wv.w };
            float xv[8] = { xv0.x, xv0.y, xv0.z, xv0.w,
                            xv1.x, xv1.y, xv1.z, xv1.w };
            #pragma unroll
            for (int i = 0; i < 8; ++i) {
                v2f xs = { xv[i], xv[i] };
                acc[i][0] = __builtin_elementwise_fma(xs, w0, acc[i][0]);
                acc[i][1] = __builtin_elementwise_fma(xs, w1, acc[i][1]);
            }
        }
    }

    #pragma unroll
    for (int i = 0; i < 8; ++i) {
        int grow = row0 + row8 + i;
        if (grow < n) {
            float d = dis[grow];
            float4 o = make_float4(acc[i][0].x * d, acc[i][0].y * d,
                                   acc[i][1].x * d, acc[i][1].y * d);
            *(float4*)(H + (size_t)grow * 64 + col4) = o;
        }
    }
}

// Wave per node: 4 edges x 16 lanes x float4. Indices prefetched (1 coalesced
// load, deg<=64 fast path), broadcast via shfl -> 16 independent gathers.
// All __shfl in wave-uniform flow; loads/adds predicated separately.
template<bool FUSE>
__global__ __launch_bounds__(256) void k_gather(const float* __restrict__ hp,
                                                const int* __restrict__ csr,
                                                const int* __restrict__ off,
                                                const int* __restrict__ cnt,
                                                const float* __restrict__ dis,
                                                const float* __restrict__ bias,
                                                float* __restrict__ outb,
                                                const float* __restrict__ Wfc,
                                                const float* __restrict__ bfc,
                                                int n) {
    int lane = threadIdx.x & 63;
    int wid  = (blockIdx.x * blockDim.x + threadIdx.x) >> 6;
    if (wid >= n) return;                      // wave-uniform (wave per node)
    int d    = wid;
    int esub = lane >> 4;
    int c4   = (lane & 15) * 4;

    int start = off[d], num = cnt[d];
    int idx = (lane < num) ? csr[start + lane] : 0;   // all indices (deg<=64)

    float4 a0 = make_float4(0.f, 0.f, 0.f, 0.f);
    float4 a1 = make_float4(0.f, 0.f, 0.f, 0.f);
    float4 a2 = make_float4(0.f, 0.f, 0.f, 0.f);
    float4 a3 = make_float4(0.f, 0.f, 0.f, 0.f);
    if (esub == 0)
        a0 = *(const float4*)(hp + (size_t)d * 64 + c4);  // self-loop

    int lim = min(num, 64);
    int j = 0;
    for (; j + 16 <= lim; j += 16) {           // uniform trip count: all active
        int s0 = __shfl(idx, j + esub);
        int s1 = __shfl(idx, j + 4 + esub);
        int s2 = __shfl(idx, j + 8 + esub);
        int s3 = __shfl(idx, j + 12 + esub);
        float4 v0 = *(const float4*)(hp + (size_t)s0 * 64 + c4);
        float4 v1 = *(const float4*)(hp + (size_t)s1 * 64 + c4);
        float4 v2 = *(const float4*)(hp + (size_t)s2 * 64 + c4);
        float4 v3 = *(const float4*)(hp + (size_t)s3 * 64 + c4);
        a0.x += v0.x; a0.y += v0.y; a0.z += v0.z; a0.w += v0.w;
        a1.x += v1.x; a1.y += v1.y; a1.z += v1.z; a1.w += v1.w;
        a2.x += v2.x; a2.y += v2.y; a2.z += v2.z; a2.w += v2.w;
        a3.x += v3.x; a3.y += v3.y; a3.z += v3.z; a3.w += v3.w;
    }
    for (; j < lim; j += 4) {                  // uniform trip count
        int jj = j + esub;                     // jj <= 63 here
        int s = __shfl(idx, jj);               // shfl OUTSIDE the branch
        if (jj < lim) {                        // only load/add predicated
            float4 v = *(const float4*)(hp + (size_t)s * 64 + c4);
            a0.x += v.x; a0.y += v.y; a0.z += v.z; a0.w += v.w;
        }
    }
    for (int j2 = 64; j2 < num; j2 += 4) {     // deg>64: essentially never
        int jj = j2 + esub;
        if (jj < num) {
            int s = csr[start + jj];           // direct load, no shfl
            float4 v = *(const float4*)(hp + (size_t)s * 64 + c4);
            a1.x += v.x; a1.y += v.y; a1.z += v.z; a1.w += v.w;
        }
    }
    a0.x += a1.x + a2.x + a3.x;
    a0.y += a1.y + a2.y + a3.y;
    a0.z += a1.z + a2.z + a3.z;
    a0.w += a1.w + a2.w + a3.w;
    #pragma unroll
    for (int o = 16; o <= 32; o <<= 1) {
        a0.x += __shfl_xor(a0.x, o);
        a0.y += __shfl_xor(a0.y, o);
        a0.z += __shfl_xor(a0.z, o);
        a0.w += __shfl_xor(a0.w, o);
    }
    float dd = dis[d];
    float4 bb = *(const float4*)(bias + c4);
    float4 o;
    o.x = fmaxf(bb.x + dd * a0.x, 0.f);
    o.y = fmaxf(bb.y + dd * a0.y, 0.f);
    o.z = fmaxf(bb.z + dd * a0.z, 0.f);
    o.w = fmaxf(bb.w + dd * a0.w, 0.f);
    if (!FUSE) {
        if (esub == 0)
            *(float4*)(outb + (size_t)d * 64 + c4) = o;
    } else {
        const float4* W4 = (const float4*)Wfc;   // row r -> Wfc[r][0..3]
        float4 w0 = W4[c4 + 0], w1 = W4[c4 + 1], w2 = W4[c4 + 2], w3 = W4[c4 + 3];
        float4 p;
        p.x = o.x * w0.x + o.y * w1.x + o.z * w2.x + o.w * w3.x;
        p.y = o.x * w0.y + o.y * w1.y + o.z * w2.y + o.w * w3.y;
        p.z = o.x * w0.z + o.y * w1.z + o.z * w2.z + o.w * w3.z;
        p.w = o.x * w0.w + o.y * w1.w + o.z * w2.w + o.w * w3.w;
        #pragma unroll
        for (int q = 1; q <= 8; q <<= 1) {
            p.x += __shfl_xor(p.x, q);
            p.y += __shfl_xor(p.y, q);
            p.z += __shfl_xor(p.z, q);
            p.w += __shfl_xor(p.w, q);
        }
        if (lane == 0) {
            float4 bf = *(const float4*)bfc;
            float4 r = make_float4(p.x + bf.x, p.y + bf.y, p.z + bf.z, p.w + bf.w);
            ((float4*)outb)[d] = r;
        }
    }
}

static inline size_t align256(size_t x) { return (x + 255) & ~(size_t)255; }

extern "C" void kernel_launch(void* const* d_in, const int* in_sizes, int n_in,
                              void* d_out, int out_size, void* d_ws, size_t ws_size,
                              hipStream_t stream) {
    const float* x   = (const float*)d_in[0];
    const int*   ei  = (const int*)d_in[1];
    const float* W1  = (const float*)d_in[2];
    const float* b1  = (const float*)d_in[3];
    const float* W2  = (const float*)d_in[4];
    const float* b2  = (const float*)d_in[5];
    const float* Wfc = (const float*)d_in[6];
    const float* bfc = (const float*)d_in[7];
    float* out = (float*)d_out;

    int n = in_sizes[0] / 128;   // 100000
    int e = in_sizes[1] / 2;     // 1600000
    const int* src = ei;
    const int* dst = ei + e;

    char* ws = (char*)d_ws;
    size_t p = 0;
    float* dis    = (float*)(ws + p); p = align256(p + (size_t)n * 4);
    int*   counts = (int*)  (ws + p); p = align256(p + (size_t)n * 4);
    int*   offs   = (int*)  (ws + p); p = align256(p + (size_t)n * 4);
    int*   bcnt   = (int*)  (ws + p); p = align256(p + 512 * 4);
    int*   bbase  = (int*)  (ws + p); p = align256(p + 512 * 4);
    int*   bcur   = (int*)  (ws + p); p = align256(p + 512 * 4);
    int*   csr    = (int*)  (ws + p); p = align256(p + (size_t)e * 4);
    float* bufA   = (float*)(ws + p); p = align256(p + (size_t)n * 64 * 4);
    float* bufB   = (float*)(ws + p);
    unsigned* binned = (unsigned*)bufB;  // alias: binned dead before bufB write

    int gb = (n + 127) / 128;        // gemm tiles
    int nbk = (n + 255) / 256;       // buckets = 391

    // CSR build (two-level multisplit) + deg/dis/offs
    k_zero_i<<<2, 256, 0, stream>>>(bcnt, 512);
    k_bcount<<<256, 256, 0, stream>>>(dst, e, bcnt);
    k_bscan<<<1, 512, 0, stream>>>(bcnt, bbase, bcur);
    k_bin<<<256, 256, 0, stream>>>(src, dst, e, bcur, binned);
    k_bucket<<<nbk, 256, 0, stream>>>(binned, bbase, bcnt, n, offs, counts, dis, csr);

    // layer 1
    k_gemm_t<128><<<gb, 256, 0, stream>>>(x, W1, dis, bufA, n);
    k_gather<false><<<(n * 64 + 255) / 256, 256, 0, stream>>>(
        bufA, csr, offs, counts, dis, b1, bufB, nullptr, nullptr, n);

    // layer 2 + fused final projection
    k_gemm_t<64><<<gb, 256, 0, stream>>>(bufB, W2, dis, bufA, n);
    k_gather<true><<<(n * 64 + 255) / 256, 256, 0, stream>>>(
        bufA, csr, offs, counts, dis, b2, out, Wfc, bfc, n);
}

// Round 7
// 323.225 us; speedup vs baseline: 3.6630x; 1.0097x over previous
//
#include <hip/hip_runtime.h>

// GCN via two-level multisplit CSR build + gather (no fp32 atomics anywhere):
//   bucket = dst>>8 (391 buckets of 256 nodes)
//   k_bcount: global bucket histogram (LDS-aggregated)
//   k_bscan : exclusive scan of bucket counts -> bbase, bcur
//   k_bin   : partition edges into bucket-contiguous packed u32 (src<<8|ldst)
//   k_bucket: per-bucket local counting sort -> csr, offs, cnt, dis (coalesced)
//   h1' = (x@W1)*dis ; a1 = relu(b1 + dis*(h1'[d] + sum_{e->d} h1'[src]))
//   h2' = (a1@W2)*dis; out = relu(b2 + dis*(...)) @ Wfc + bfc  (final fused)
// GEMMs: register-tiled 128x64, v2f accumulators (v_pk_fma_f32); epilogue
// also writes a ZERO ROW at index n (used by gather to mask padded edges
// without predicating loads).
// Gather: wave/node, indices prefetched+shfl-broadcast; edges processed in
// padded 32-edge batches with 8 branch-free independent loads in flight
// (out-of-range slots clamp to the zero row) -> max memory-level parallelism.

typedef float v2f __attribute__((ext_vector_type(2)));

__global__ __launch_bounds__(256) void k_bcount(const int* __restrict__ dst, int e,
                                                int* __restrict__ bcnt) {
    __shared__ int lh[512];
    for (int i = threadIdx.x; i < 512; i += 256) lh[i] = 0;
    __syncthreads();
    for (int i = blockIdx.x * blockDim.x + threadIdx.x; i < e;
         i += gridDim.x * blockDim.x)
        atomicAdd(&lh[dst[i] >> 8], 1);
    __syncthreads();
    for (int i = threadIdx.x; i < 512; i += 256)
        if (lh[i]) atomicAdd(&bcnt[i], lh[i]);
}

__global__ __launch_bounds__(512) void k_bscan(const int* __restrict__ bcnt,
                                               int* __restrict__ bbase,
                                               int* __restrict__ bcur) {
    __shared__ int tmp[512];
    int t = threadIdx.x;
    int v = bcnt[t];
    tmp[t] = v;
    __syncthreads();
    for (int o = 1; o < 512; o <<= 1) {
        int x = (t >= o) ? tmp[t - o] : 0;
        __syncthreads();
        tmp[t] += x;
        __syncthreads();
    }
    int ex = tmp[t] - v;
    bbase[t] = ex;
    bcur[t] = ex;
}

// Partition edges into bucket-contiguous runs of packed u32 (src<<8 | ldst).
__global__ __launch_bounds__(256) void k_bin(const int* __restrict__ src,
                                             const int* __restrict__ dst, int e,
                                             int* bcur, unsigned* __restrict__ binned) {
    __shared__ int lh[512], lbase[512], lr[512];
    int t = threadIdx.x;
    for (int i = t; i < 512; i += 256) { lh[i] = 0; lr[i] = 0; }
    __syncthreads();
    int chunk = (e + gridDim.x - 1) / gridDim.x;
    int lo = blockIdx.x * chunk;
    int hi = min(e, lo + chunk);
    for (int i = lo + t; i < hi; i += 256)
        atomicAdd(&lh[dst[i] >> 8], 1);
    __syncthreads();
    for (int i = t; i < 512; i += 256)
        lbase[i] = lh[i] ? atomicAdd(&bcur[i], lh[i]) : 0;
    __syncthreads();
    for (int i = lo + t; i < hi; i += 256) {
        int d = dst[i];
        int b = d >> 8;
        int r = atomicAdd(&lr[b], 1);
        binned[lbase[b] + r] = ((unsigned)src[i] << 8) | (unsigned)(d & 255);
    }
}

// One block per bucket: counting sort of <=~4500 edges over 256 local nodes.
__global__ __launch_bounds__(256) void k_bucket(const unsigned* __restrict__ binned,
                                                const int* __restrict__ bbase,
                                                const int* __restrict__ bcnt,
                                                int n, int* __restrict__ offs,
                                                int* __restrict__ cnt,
                                                float* __restrict__ dis,
                                                int* __restrict__ csr) {
    __shared__ int nh[256], nsc[256], nr[256];
    int b = blockIdx.x, t = threadIdx.x;
    int node0 = b << 8;
    int ebase = bbase[b], ecnt = bcnt[b];
    nh[t] = 0; nr[t] = 0;
    __syncthreads();
    for (int j = t; j < ecnt; j += 256)
        atomicAdd(&nh[binned[ebase + j] & 255u], 1);
    __syncthreads();
    int v = nh[t];
    nsc[t] = v;
    __syncthreads();
    for (int o = 1; o < 256; o <<= 1) {
        int x = (t >= o) ? nsc[t - o] : 0;
        __syncthreads();
        nsc[t] += x;
        __syncthreads();
    }
    int ex = nsc[t] - v;
    int d = node0 + t;
    if (d < n) {
        offs[d] = ebase + ex;
        cnt[d]  = v;
        dis[d]  = rsqrtf((float)(v + 1));   // +1 self-loop
    }
    nsc[t] = ex;
    __syncthreads();
    for (int j = t; j < ecnt; j += 256) {
        unsigned ed = binned[ebase + j];
        int ld = ed & 255u;
        int r = atomicAdd(&nr[ld], 1);
        csr[ebase + nsc[ld] + r] = (int)(ed >> 8);
    }
}

// Register-tiled GEMM: X[n,K] @ W[K,64] -> H[row][col] = acc * dis[row].
// Also writes zeros to row n (the gather's mask row). H has n+1 rows.
template<int K>
__global__ __launch_bounds__(256) void k_gemm_t(const float* __restrict__ X,
                                                const float* __restrict__ W,
                                                const float* __restrict__ dis,
                                                float* __restrict__ H, int n) {
    constexpr int BM = 128, CK = 32, XS = BM + 4;
    __shared__ float ws[K * 64];
    __shared__ float xT[CK * XS];

    int t = threadIdx.x;
    for (int i = t; i < K * 16; i += 256)
        ((float4*)ws)[i] = ((const float4*)W)[i];

    int row0 = blockIdx.x * BM;
    int col4 = (t & 15) * 4;
    int row8 = (t >> 4) * 8;
    int kq   = t & 7;
    int rr   = t >> 3;

    v2f acc[8][2] = {};

    for (int kc = 0; kc < K; kc += CK) {
        __syncthreads();
        #pragma unroll
        for (int p = 0; p < 4; ++p) {
            int row  = p * 32 + rr;
            int grow = row0 + row;
            float4 v = make_float4(0.f, 0.f, 0.f, 0.f);
            if (grow < n)
                v = *(const float4*)(X + (size_t)grow * K + kc + kq * 4);
            xT[(kq * 4 + 0) * XS + row] = v.x;
            xT[(kq * 4 + 1) * XS + row] = v.y;
            xT[(kq * 4 + 2) * XS + row] = v.z;
            xT[(kq * 4 + 3) * XS + row] = v.w;
        }
        __syncthreads();
        #pragma unroll
        for (int k = 0; k < CK; ++k) {
            float4 wv  = *(const float4*)(ws + (kc + k) * 64 + col4);
            float4 xv0 = *(const float4*)(xT + k * XS + row8);
            float4 xv1 = *(const float4*)(xT + k * XS + row8 + 4);
            v2f w0 = { wv.x, wv.y };
            v2f w1 = { wv.z, wv.w };
            float xv[8] = { xv0.x, xv0.y, xv0.z, xv0.w,
                            xv1.x, xv1.y, xv1.z, xv1.w };
            #pragma unroll
            for (int i = 0; i < 8; ++i) {
                v2f xs = { xv[i], xv[i] };
                acc[i][0] = __builtin_elementwise_fma(xs, w0, acc[i][0]);
                acc[i][1] = __builtin_elementwise_fma(xs, w1, acc[i][1]);
            }
        }
    }

    #pragma unroll
    for (int i = 0; i < 8; ++i) {
        int grow = row0 + row8 + i;
        if (grow < n) {
            float d = dis[grow];
            float4 o = make_float4(acc[i][0].x * d, acc[i][0].y * d,
                                   acc[i][1].x * d, acc[i][1].y * d);
            *(float4*)(H + (size_t)grow * 64 + col4) = o;
        } else if (grow == n) {   // zero mask-row for the gather
            *(float4*)(H + (size_t)grow * 64 + col4) =
                make_float4(0.f, 0.f, 0.f, 0.f);
        }
    }
}

// Wave per node: 4 edges x 16 lanes x float4. Indices prefetched; edges in
// padded 32-edge batches -> 8 branch-free independent loads in flight
// (out-of-range slots read the zero row at index n). All __shfl wave-uniform.
template<bool FUSE>
__global__ __launch_bounds__(256) void k_gather(const float* __restrict__ hp,
                                                const int* __restrict__ csr,
                                                const int* __restrict__ off,
                                                const int* __restrict__ cnt,
                                                const float* __restrict__ dis,
                                                const float* __restrict__ bias,
                                                float* __restrict__ outb,
                                                const float* __restrict__ Wfc,
                                                const float* __restrict__ bfc,
                                                int n) {
    int lane = threadIdx.x & 63;
    int wid  = (blockIdx.x * blockDim.x + threadIdx.x) >> 6;
    if (wid >= n) return;                      // wave-uniform (wave per node)
    int d    = wid;
    int esub = lane >> 4;
    int c4   = (lane & 15) * 4;

    int start = off[d], num = cnt[d];
    int idx = (lane < num) ? csr[start + lane] : 0;   // all indices (deg<=64)
    int lim = min(num, 64);

    float4 a0 = make_float4(0.f, 0.f, 0.f, 0.f);
    float4 a1 = make_float4(0.f, 0.f, 0.f, 0.f);
    float4 a2 = make_float4(0.f, 0.f, 0.f, 0.f);
    float4 a3 = make_float4(0.f, 0.f, 0.f, 0.f);
    if (esub == 0)
        a0 = *(const float4*)(hp + (size_t)d * 64 + c4);  // self-loop

    // batch 1: edges 0..31 (covers 99.98% of nodes entirely)
    {
        int s[8];
        #pragma unroll
        for (int g = 0; g < 8; ++g) {
            int jj = g * 4 + esub;
            int sr = __shfl(idx, jj);          // uniform exec
            s[g] = (jj < lim) ? sr : n;        // pad -> zero row
        }
        float4 v0 = *(const float4*)(hp + (size_t)s[0] * 64 + c4);
        float4 v1 = *(const float4*)(hp + (size_t)s[1] * 64 + c4);
        float4 v2 = *(const float4*)(hp + (size_t)s[2] * 64 + c4);
        float4 v3 = *(const float4*)(hp + (size_t)s[3] * 64 + c4);
        float4 v4 = *(const float4*)(hp + (size_t)s[4] * 64 + c4);
        float4 v5 = *(const float4*)(hp + (size_t)s[5] * 64 + c4);
        float4 v6 = *(const float4*)(hp + (size_t)s[6] * 64 + c4);
        float4 v7 = *(const float4*)(hp + (size_t)s[7] * 64 + c4);
        a0.x += v0.x; a0.y += v0.y; a0.z += v0.z; a0.w += v0.w;
        a1.x += v1.x; a1.y += v1.y; a1.z += v1.z; a1.w += v1.w;
        a2.x += v2.x; a2.y += v2.y; a2.z += v2.z; a2.w += v2.w;
        a3.x += v3.x; a3.y += v3.y; a3.z += v3.z; a3.w += v3.w;
        a0.x += v4.x; a0.y += v4.y; a0.z += v4.z; a0.w += v4.w;
        a1.x += v5.x; a1.y += v5.y; a1.z += v5.z; a1.w += v5.w;
        a2.x += v6.x; a2.y += v6.y; a2.z += v6.z; a2.w += v6.w;
        a3.x += v7.x; a3.y += v7.y; a3.z += v7.z; a3.w += v7.w;
    }
    if (lim > 32) {                            // batch 2: edges 32..63
        int s[8];
        #pragma unroll
        for (int g = 0; g < 8; ++g) {
            int jj = 32 + g * 4 + esub;
            int sr = __shfl(idx, jj);
            s[g] = (jj < lim) ? sr : n;
        }
        float4 v0 = *(const float4*)(hp + (size_t)s[0] * 64 + c4);
        float4 v1 = *(const float4*)(hp + (size_t)s[1] * 64 + c4);
        float4 v2 = *(const float4*)(hp + (size_t)s[2] * 64 + c4);
        float4 v3 = *(const float4*)(hp + (size_t)s[3] * 64 + c4);
        float4 v4 = *(const float4*)(hp + (size_t)s[4] * 64 + c4);
        float4 v5 = *(const float4*)(hp + (size_t)s[5] * 64 + c4);
        float4 v6 = *(const float4*)(hp + (size_t)s[6] * 64 + c4);
        float4 v7 = *(const float4*)(hp + (size_t)s[7] * 64 + c4);
        a0.x += v0.x; a0.y += v0.y; a0.z += v0.z; a0.w += v0.w;
        a1.x += v1.x; a1.y += v1.y; a1.z += v1.z; a1.w += v1.w;
        a2.x += v2.x; a2.y += v2.y; a2.z += v2.z; a2.w += v2.w;
        a3.x += v3.x; a3.y += v3.y; a3.z += v3.z; a3.w += v3.w;
        a0.x += v4.x; a0.y += v4.y; a0.z += v4.z; a0.w += v4.w;
        a1.x += v5.x; a1.y += v5.y; a1.z += v5.z; a1.w += v5.w;
        a2.x += v6.x; a2.y += v6.y; a2.z += v6.z; a2.w += v6.w;
        a3.x += v7.x; a3.y += v7.y; a3.z += v7.z; a3.w += v7.w;
    }
    for (int j2 = 64; j2 < num; j2 += 4) {     // deg>64: essentially never
        int jj = j2 + esub;
        if (jj < num) {
            int s = csr[start + jj];           // direct load, no shfl
            float4 v = *(const float4*)(hp + (size_t)s * 64 + c4);
            a1.x += v.x; a1.y += v.y; a1.z += v.z; a1.w += v.w;
        }
    }
    a0.x += a1.x + a2.x + a3.x;
    a0.y += a1.y + a2.y + a3.y;
    a0.z += a1.z + a2.z + a3.z;
    a0.w += a1.w + a2.w + a3.w;
    #pragma unroll
    for (int o = 16; o <= 32; o <<= 1) {
        a0.x += __shfl_xor(a0.x, o);
        a0.y += __shfl_xor(a0.y, o);
        a0.z += __shfl_xor(a0.z, o);
        a0.w += __shfl_xor(a0.w, o);
    }
    float dd = dis[d];
    float4 bb = *(const float4*)(bias + c4);
    float4 o;
    o.x = fmaxf(bb.x + dd * a0.x, 0.f);
    o.y = fmaxf(bb.y + dd * a0.y, 0.f);
    o.z = fmaxf(bb.z + dd * a0.z, 0.f);
    o.w = fmaxf(bb.w + dd * a0.w, 0.f);
    if (!FUSE) {
        if (esub == 0)
            *(float4*)(outb + (size_t)d * 64 + c4) = o;
    } else {
        const float4* W4 = (const float4*)Wfc;   // row r -> Wfc[r][0..3]
        float4 w0 = W4[c4 + 0], w1 = W4[c4 + 1], w2 = W4[c4 + 2], w3 = W4[c4 + 3];
        float4 p;
        p.x = o.x * w0.x + o.y * w1.x + o.z * w2.x + o.w * w3.x;
        p.y = o.x * w0.y + o.y * w1.y + o.z * w2.y + o.w * w3.y;
        p.z = o.x * w0.z + o.y * w1.z + o.z * w2.z + o.w * w3.z;
        p.w = o.x * w0.w + o.y * w1.w + o.z * w2.w + o.w * w3.w;
        #pragma unroll
        for (int q = 1; q <= 8; q <<= 1) {
            p.x += __shfl_xor(p.x, q);
            p.y += __shfl_xor(p.y, q);
            p.z += __shfl_xor(p.z, q);
            p.w += __shfl_xor(p.w, q);
        }
        if (lane == 0) {
            float4 bf = *(const float4*)bfc;
            float4 r = make_float4(p.x + bf.x, p.y + bf.y, p.z + bf.z, p.w + bf.w);
            ((float4*)outb)[d] = r;
        }
    }
}

static inline size_t align256(size_t x) { return (x + 255) & ~(size_t)255; }

extern "C" void kernel_launch(void* const* d_in, const int* in_sizes, int n_in,
                              void* d_out, int out_size, void* d_ws, size_t ws_size,
                              hipStream_t stream) {
    const float* x   = (const float*)d_in[0];
    const int*   ei  = (const int*)d_in[1];
    const float* W1  = (const float*)d_in[2];
    const float* b1  = (const float*)d_in[3];
    const float* W2  = (const float*)d_in[4];
    const float* b2  = (const float*)d_in[5];
    const float* Wfc = (const float*)d_in[6];
    const float* bfc = (const float*)d_in[7];
    float* out = (float*)d_out;

    int n = in_sizes[0] / 128;   // 100000
    int e = in_sizes[1] / 2;     // 1600000
    const int* src = ei;
    const int* dst = ei + e;

    char* ws = (char*)d_ws;
    size_t p = 0;
    float* dis    = (float*)(ws + p); p = align256(p + (size_t)n * 4);
    int*   counts = (int*)  (ws + p); p = align256(p + (size_t)n * 4);
    int*   offs   = (int*)  (ws + p); p = align256(p + (size_t)n * 4);
    int*   bcnt   = (int*)  (ws + p); p = align256(p + 512 * 4);
    int*   bbase  = (int*)  (ws + p); p = align256(p + 512 * 4);
    int*   bcur   = (int*)  (ws + p); p = align256(p + 512 * 4);
    int*   csr    = (int*)  (ws + p); p = align256(p + (size_t)e * 4);
    float* bufA   = (float*)(ws + p); p = align256(p + (size_t)(n + 1) * 64 * 4);
    float* bufB   = (float*)(ws + p);
    unsigned* binned = (unsigned*)bufB;  // alias: binned dead before bufB write

    int gb = (n + 127) / 128;        // gemm tiles (covers row n for zero-row)
    int nbk = (n + 255) / 256;       // buckets = 391

    // CSR build (two-level multisplit) + deg/dis/offs
    hipMemsetAsync(bcnt, 0, 512 * sizeof(int), stream);
    k_bcount<<<256, 256, 0, stream>>>(dst, e, bcnt);
    k_bscan<<<1, 512, 0, stream>>>(bcnt, bbase, bcur);
    k_bin<<<256, 256, 0, stream>>>(src, dst, e, bcur, binned);
    k_bucket<<<nbk, 256, 0, stream>>>(binned, bbase, bcnt, n, offs, counts, dis, csr);

    // layer 1
    k_gemm_t<128><<<gb, 256, 0, stream>>>(x, W1, dis, bufA, n);
    k_gather<false><<<(n * 64 + 255) / 256, 256, 0, stream>>>(
        bufA, csr, offs, counts, dis, b1, bufB, nullptr, nullptr, n);

    // layer 2 + fused final projection
    k_gemm_t<64><<<gb, 256, 0, stream>>>(bufB, W2, dis, bufA, n);
    k_gather<true><<<(n * 64 + 255) / 256, 256, 0, stream>>>(
        bufA, csr, offs, counts, dis, b2, out, Wfc, bfc, n);
}

// Round 8
// 296.733 us; speedup vs baseline: 3.9900x; 1.0893x over previous
//
#include <hip/hip_runtime.h>
#include <hip/hip_fp16.h>

// GCN via two-level multisplit CSR build + fp16-row gather:
//   bucket = dst>>8 (391 buckets of 256 nodes)
//   k_bcount/k_bscan/k_bin/k_bucket: CSR-by-dst, no fp32 atomics
//   h1' = fp16((x@W1)*dis); a1 = relu(b1 + dis*(h1'[d] + sum h1'[src]))  [fp32]
//   h2' = fp16((a1@W2)*dis); out = relu(b2 + dis*(...)) @ Wfc + bfc (fused)
// Rationale: gather is bandwidth-limited on the L3->L2 random-row path
// (~3 TB/s observed, R6/R7); fp16 rows halve the compulsory per-XCD traffic
// (256B -> 128B rows). Accumulation stays fp32; only gathered tables are fp16.
// GEMMs: register-tiled 128x64, v2f acc (v_pk_fma_f32), fp16 epilogue + a
// zero row at index n used to mask padded gather slots without predication.

typedef float v2f __attribute__((ext_vector_type(2)));

__global__ __launch_bounds__(256) void k_bcount(const int* __restrict__ dst, int e,
                                                int* __restrict__ bcnt) {
    __shared__ int lh[512];
    for (int i = threadIdx.x; i < 512; i += 256) lh[i] = 0;
    __syncthreads();
    for (int i = blockIdx.x * blockDim.x + threadIdx.x; i < e;
         i += gridDim.x * blockDim.x)
        atomicAdd(&lh[dst[i] >> 8], 1);
    __syncthreads();
    for (int i = threadIdx.x; i < 512; i += 256)
        if (lh[i]) atomicAdd(&bcnt[i], lh[i]);
}

__global__ __launch_bounds__(512) void k_bscan(const int* __restrict__ bcnt,
                                               int* __restrict__ bbase,
                                               int* __restrict__ bcur) {
    __shared__ int tmp[512];
    int t = threadIdx.x;
    int v = bcnt[t];
    tmp[t] = v;
    __syncthreads();
    for (int o = 1; o < 512; o <<= 1) {
        int x = (t >= o) ? tmp[t - o] : 0;
        __syncthreads();
        tmp[t] += x;
        __syncthreads();
    }
    int ex = tmp[t] - v;
    bbase[t] = ex;
    bcur[t] = ex;
}

// Partition edges into bucket-contiguous runs of packed u32 (src<<8 | ldst).
__global__ __launch_bounds__(256) void k_bin(const int* __restrict__ src,
                                             const int* __restrict__ dst, int e,
                                             int* bcur, unsigned* __restrict__ binned) {
    __shared__ int lh[512], lbase[512], lr[512];
    int t = threadIdx.x;
    for (int i = t; i < 512; i += 256) { lh[i] = 0; lr[i] = 0; }
    __syncthreads();
    int chunk = (e + gridDim.x - 1) / gridDim.x;
    int lo = blockIdx.x * chunk;
    int hi = min(e, lo + chunk);
    for (int i = lo + t; i < hi; i += 256)
        atomicAdd(&lh[dst[i] >> 8], 1);
    __syncthreads();
    for (int i = t; i < 512; i += 256)
        lbase[i] = lh[i] ? atomicAdd(&bcur[i], lh[i]) : 0;
    __syncthreads();
    for (int i = lo + t; i < hi; i += 256) {
        int d = dst[i];
        int b = d >> 8;
        int r = atomicAdd(&lr[b], 1);
        binned[lbase[b] + r] = ((unsigned)src[i] << 8) | (unsigned)(d & 255);
    }
}

// One block per bucket: counting sort of <=~4500 edges over 256 local nodes.
__global__ __launch_bounds__(256) void k_bucket(const unsigned* __restrict__ binned,
                                                const int* __restrict__ bbase,
                                                const int* __restrict__ bcnt,
                                                int n, int* __restrict__ offs,
                                                int* __restrict__ cnt,
                                                float* __restrict__ dis,
                                                int* __restrict__ csr) {
    __shared__ int nh[256], nsc[256], nr[256];
    int b = blockIdx.x, t = threadIdx.x;
    int node0 = b << 8;
    int ebase = bbase[b], ecnt = bcnt[b];
    nh[t] = 0; nr[t] = 0;
    __syncthreads();
    for (int j = t; j < ecnt; j += 256)
        atomicAdd(&nh[binned[ebase + j] & 255u], 1);
    __syncthreads();
    int v = nh[t];
    nsc[t] = v;
    __syncthreads();
    for (int o = 1; o < 256; o <<= 1) {
        int x = (t >= o) ? nsc[t - o] : 0;
        __syncthreads();
        nsc[t] += x;
        __syncthreads();
    }
    int ex = nsc[t] - v;
    int d = node0 + t;
    if (d < n) {
        offs[d] = ebase + ex;
        cnt[d]  = v;
        dis[d]  = rsqrtf((float)(v + 1));   // +1 self-loop
    }
    nsc[t] = ex;
    __syncthreads();
    for (int j = t; j < ecnt; j += 256) {
        unsigned ed = binned[ebase + j];
        int ld = ed & 255u;
        int r = atomicAdd(&nr[ld], 1);
        csr[ebase + nsc[ld] + r] = (int)(ed >> 8);
    }
}

// Register-tiled GEMM: X[n,K](fp32) @ W[K,64] -> H[row][col] (fp16) = acc*dis.
// Also writes a zero row at index n (gather mask row). H has n+1 rows.
template<int K>
__global__ __launch_bounds__(256) void k_gemm_t(const float* __restrict__ X,
                                                const float* __restrict__ W,
                                                const float* __restrict__ dis,
                                                __half* __restrict__ H, int n) {
    constexpr int BM = 128, CK = 32, XS = BM + 4;
    __shared__ float ws[K * 64];
    __shared__ float xT[CK * XS];

    int t = threadIdx.x;
    for (int i = t; i < K * 16; i += 256)
        ((float4*)ws)[i] = ((const float4*)W)[i];

    int row0 = blockIdx.x * BM;
    int col4 = (t & 15) * 4;
    int row8 = (t >> 4) * 8;
    int kq   = t & 7;
    int rr   = t >> 3;

    v2f acc[8][2] = {};

    for (int kc = 0; kc < K; kc += CK) {
        __syncthreads();
        #pragma unroll
        for (int p = 0; p < 4; ++p) {
            int row  = p * 32 + rr;
            int grow = row0 + row;
            float4 v = make_float4(0.f, 0.f, 0.f, 0.f);
            if (grow < n)
                v = *(const float4*)(X + (size_t)grow * K + kc + kq * 4);
            xT[(kq * 4 + 0) * XS + row] = v.x;
            xT[(kq * 4 + 1) * XS + row] = v.y;
            xT[(kq * 4 + 2) * XS + row] = v.z;
            xT[(kq * 4 + 3) * XS + row] = v.w;
        }
        __syncthreads();
        #pragma unroll
        for (int k = 0; k < CK; ++k) {
            float4 wv  = *(const float4*)(ws + (kc + k) * 64 + col4);
            float4 xv0 = *(const float4*)(xT + k * XS + row8);
            float4 xv1 = *(const float4*)(xT + k * XS + row8 + 4);
            v2f w0 = { wv.x, wv.y };
            v2f w1 = { wv.z, wv.w };
            float xv[8] = { xv0.x, xv0.y, xv0.z, xv0.w,
                            xv1.x, xv1.y, xv1.z, xv1.w };
            #pragma unroll
            for (int i = 0; i < 8; ++i) {
                v2f xs = { xv[i], xv[i] };
                acc[i][0] = __builtin_elementwise_fma(xs, w0, acc[i][0]);
                acc[i][1] = __builtin_elementwise_fma(xs, w1, acc[i][1]);
            }
        }
    }

    #pragma unroll
    for (int i = 0; i < 8; ++i) {
        int grow = row0 + row8 + i;
        if (grow < n) {
            float d = dis[grow];
            union { __half2 h[2]; float2 f; } u;
            u.h[0] = __floats2half2_rn(acc[i][0].x * d, acc[i][0].y * d);
            u.h[1] = __floats2half2_rn(acc[i][1].x * d, acc[i][1].y * d);
            *(float2*)(H + (size_t)grow * 64 + col4) = u.f;
        } else if (grow == n) {   // zero mask-row for the gather
            *(float2*)(H + (size_t)grow * 64 + col4) = make_float2(0.f, 0.f);
        }
    }
}

__device__ inline void add_row(const __half* __restrict__ hp, int s, int c4,
                               v2f& lo, v2f& hi) {
    float2 raw = *(const float2*)(hp + (size_t)s * 64 + c4);   // 4 halves
    const __half2* p = (const __half2*)&raw;
    float2 l = __half22float2(p[0]);
    float2 h = __half22float2(p[1]);
    lo += (v2f){ l.x, l.y };
    hi += (v2f){ h.x, h.y };
}

// Wave per node: 4 edges x 16 lanes x 4 fp16 channels. Indices prefetched and
// shfl-broadcast (wave-uniform exec — divergent shfl was the R5 bug). Full
// 16-edge batches are clamp-free; 4-step tail clamps pad slots to zero row n.
template<bool FUSE>
__global__ __launch_bounds__(256) void k_gather(const __half* __restrict__ hp,
                                                const int* __restrict__ csr,
                                                const int* __restrict__ off,
                                                const int* __restrict__ cnt,
                                                const float* __restrict__ dis,
                                                const float* __restrict__ bias,
                                                float* __restrict__ outb,
                                                const float* __restrict__ Wfc,
                                                const float* __restrict__ bfc,
                                                int n) {
    int lane = threadIdx.x & 63;
    int wid  = (blockIdx.x * blockDim.x + threadIdx.x) >> 6;
    if (wid >= n) return;                      // wave-uniform (wave per node)
    int d    = wid;
    int esub = lane >> 4;
    int c4   = (lane & 15) * 4;

    int start = off[d], num = cnt[d];
    int idx = (lane < num) ? csr[start + lane] : 0;   // all indices (deg<=64)
    int lim = min(num, 64);

    v2f aL[4] = {}, aH[4] = {};
    if (esub == 0)
        add_row(hp, d, c4, aL[0], aH[0]);      // self-loop

    int j = 0;
    for (; j + 16 <= lim; j += 16) {           // full batches: no clamp needed
        int s0 = __shfl(idx, j + esub);
        int s1 = __shfl(idx, j + 4 + esub);
        int s2 = __shfl(idx, j + 8 + esub);
        int s3 = __shfl(idx, j + 12 + esub);
        add_row(hp, s0, c4, aL[0], aH[0]);
        add_row(hp, s1, c4, aL[1], aH[1]);
        add_row(hp, s2, c4, aL[2], aH[2]);
        add_row(hp, s3, c4, aL[3], aH[3]);
    }
    for (; j < lim; j += 4) {                  // tail: clamp pads to zero row
        int jj = j + esub;                     // jj <= 63 here
        int sr = __shfl(idx, jj);              // uniform exec
        int s  = (jj < lim) ? sr : n;
        add_row(hp, s, c4, aL[0], aH[0]);
    }
    for (int j2 = 64; j2 < num; j2 += 4) {     // deg>64: essentially never
        int jj = j2 + esub;
        if (jj < num) {
            int s = csr[start + jj];           // direct load, no shfl
            add_row(hp, s, c4, aL[1], aH[1]);
        }
    }
    v2f sL = (aL[0] + aL[1]) + (aL[2] + aL[3]);
    v2f sH = (aH[0] + aH[1]) + (aH[2] + aH[3]);
    float4 a0 = make_float4(sL.x, sL.y, sH.x, sH.y);
    #pragma unroll
    for (int o = 16; o <= 32; o <<= 1) {
        a0.x += __shfl_xor(a0.x, o);
        a0.y += __shfl_xor(a0.y, o);
        a0.z += __shfl_xor(a0.z, o);
        a0.w += __shfl_xor(a0.w, o);
    }
    float dd = dis[d];
    float4 bb = *(const float4*)(bias + c4);
    float4 o;
    o.x = fmaxf(bb.x + dd * a0.x, 0.f);
    o.y = fmaxf(bb.y + dd * a0.y, 0.f);
    o.z = fmaxf(bb.z + dd * a0.z, 0.f);
    o.w = fmaxf(bb.w + dd * a0.w, 0.f);
    if (!FUSE) {
        if (esub == 0)
            *(float4*)(outb + (size_t)d * 64 + c4) = o;
    } else {
        const float4* W4 = (const float4*)Wfc;   // row r -> Wfc[r][0..3]
        float4 w0 = W4[c4 + 0], w1 = W4[c4 + 1], w2 = W4[c4 + 2], w3 = W4[c4 + 3];
        float4 p;
        p.x = o.x * w0.x + o.y * w1.x + o.z * w2.x + o.w * w3.x;
        p.y = o.x * w0.y + o.y * w1.y + o.z * w2.y + o.w * w3.y;
        p.z = o.x * w0.z + o.y * w1.z + o.z * w2.z + o.w * w3.z;
        p.w = o.x * w0.w + o.y * w1.w + o.z * w2.w + o.w * w3.w;
        #pragma unroll
        for (int q = 1; q <= 8; q <<= 1) {
            p.x += __shfl_xor(p.x, q);
            p.y += __shfl_xor(p.y, q);
            p.z += __shfl_xor(p.z, q);
            p.w += __shfl_xor(p.w, q);
        }
        if (lane == 0) {
            float4 bf = *(const float4*)bfc;
            float4 r = make_float4(p.x + bf.x, p.y + bf.y, p.z + bf.z, p.w + bf.w);
            ((float4*)outb)[d] = r;
        }
    }
}

static inline size_t align256(size_t x) { return (x + 255) & ~(size_t)255; }

extern "C" void kernel_launch(void* const* d_in, const int* in_sizes, int n_in,
                              void* d_out, int out_size, void* d_ws, size_t ws_size,
                              hipStream_t stream) {
    const float* x   = (const float*)d_in[0];
    const int*   ei  = (const int*)d_in[1];
    const float* W1  = (const float*)d_in[2];
    const float* b1  = (const float*)d_in[3];
    const float* W2  = (const float*)d_in[4];
    const float* b2  = (const float*)d_in[5];
    const float* Wfc = (const float*)d_in[6];
    const float* bfc = (const float*)d_in[7];
    float* out = (float*)d_out;

    int n = in_sizes[0] / 128;   // 100000
    int e = in_sizes[1] / 2;     // 1600000
    const int* src = ei;
    const int* dst = ei + e;

    char* ws = (char*)d_ws;
    size_t p = 0;
    float*  dis    = (float*) (ws + p); p = align256(p + (size_t)n * 4);
    int*    counts = (int*)   (ws + p); p = align256(p + (size_t)n * 4);
    int*    offs   = (int*)   (ws + p); p = align256(p + (size_t)n * 4);
    int*    bcnt   = (int*)   (ws + p); p = align256(p + 512 * 4);
    int*    bbase  = (int*)   (ws + p); p = align256(p + 512 * 4);
    int*    bcur   = (int*)   (ws + p); p = align256(p + 512 * 4);
    int*    csr    = (int*)   (ws + p); p = align256(p + (size_t)e * 4);
    __half* hbuf   = (__half*)(ws + p); p = align256(p + (size_t)(n + 1) * 64 * 2);
    float*  a1     = (float*) (ws + p);                 // n*64 fp32
    unsigned* binned = (unsigned*)a1;  // alias: binned dead before a1 written

    int gb  = (n + 127) / 128;       // gemm tiles (covers row n for zero-row)
    int nbk = (n + 255) / 256;       // buckets = 391

    // CSR build (two-level multisplit) + deg/dis/offs
    hipMemsetAsync(bcnt, 0, 512 * sizeof(int), stream);
    k_bcount<<<256, 256, 0, stream>>>(dst, e, bcnt);
    k_bscan<<<1, 512, 0, stream>>>(bcnt, bbase, bcur);
    k_bin<<<256, 256, 0, stream>>>(src, dst, e, bcur, binned);
    k_bucket<<<nbk, 256, 0, stream>>>(binned, bbase, bcnt, n, offs, counts, dis, csr);

    // layer 1: h1' (fp16) -> a1 (fp32)
    k_gemm_t<128><<<gb, 256, 0, stream>>>(x, W1, dis, hbuf, n);
    k_gather<false><<<(n * 64 + 255) / 256, 256, 0, stream>>>(
        hbuf, csr, offs, counts, dis, b1, a1, nullptr, nullptr, n);

    // layer 2: h2' (fp16, reuses hbuf) -> fused final projection
    k_gemm_t<64><<<gb, 256, 0, stream>>>(a1, W2, dis, hbuf, n);
    k_gather<true><<<(n * 64 + 255) / 256, 256, 0, stream>>>(
        hbuf, csr, offs, counts, dis, b2, out, Wfc, bfc, n);
}

// Round 9
// 284.088 us; speedup vs baseline: 4.1676x; 1.0445x over previous
//
#include <hip/hip_runtime.h>
#include <hip/hip_fp16.h>

// GCN, fp16 intermediate chain + MFMA GEMMs:
//   CSR build (two-level multisplit, no fp32 atomics)
//   h1' = fp16((x@W1)*dis)        [MFMA 16x16x32_f16, fp32 acc]
//   a1  = fp16(relu(b1 + dis*(h1'[d] + sum h1'[src])))   [gather, fp32 acc]
//   h2' = fp16((a1@W2)*dis)       [MFMA]
//   out = relu(b2 + dis*(...)) @ Wfc + bfc  (gather w/ fused final, fp32 out)
// Gather is MSHR/latency-bound (~57us, R7/R8 analysis) — left structurally
// unchanged; this round removes VALU-GEMM + fp32 a1 round-trip cost.

typedef float v2f __attribute__((ext_vector_type(2)));
typedef _Float16 f16x8 __attribute__((ext_vector_type(8)));
typedef float f32x4 __attribute__((ext_vector_type(4)));

__global__ __launch_bounds__(256) void k_bcount(const int* __restrict__ dst, int e,
                                                int* __restrict__ bcnt) {
    __shared__ int lh[512];
    for (int i = threadIdx.x; i < 512; i += 256) lh[i] = 0;
    __syncthreads();
    for (int i = blockIdx.x * blockDim.x + threadIdx.x; i < e;
         i += gridDim.x * blockDim.x)
        atomicAdd(&lh[dst[i] >> 8], 1);
    __syncthreads();
    for (int i = threadIdx.x; i < 512; i += 256)
        if (lh[i]) atomicAdd(&bcnt[i], lh[i]);
}

__global__ __launch_bounds__(512) void k_bscan(const int* __restrict__ bcnt,
                                               int* __restrict__ bbase,
                                               int* __restrict__ bcur) {
    __shared__ int tmp[512];
    int t = threadIdx.x;
    int v = bcnt[t];
    tmp[t] = v;
    __syncthreads();
    for (int o = 1; o < 512; o <<= 1) {
        int x = (t >= o) ? tmp[t - o] : 0;
        __syncthreads();
        tmp[t] += x;
        __syncthreads();
    }
    int ex = tmp[t] - v;
    bbase[t] = ex;
    bcur[t] = ex;
}

// Partition edges into bucket-contiguous runs of packed u32 (src<<8 | ldst).
__global__ __launch_bounds__(256) void k_bin(const int* __restrict__ src,
                                             const int* __restrict__ dst, int e,
                                             int* bcur, unsigned* __restrict__ binned) {
    __shared__ int lh[512], lbase[512], lr[512];
    int t = threadIdx.x;
    for (int i = t; i < 512; i += 256) { lh[i] = 0; lr[i] = 0; }
    __syncthreads();
    int chunk = (e + gridDim.x - 1) / gridDim.x;
    int lo = blockIdx.x * chunk;
    int hi = min(e, lo + chunk);
    for (int i = lo + t; i < hi; i += 256)
        atomicAdd(&lh[dst[i] >> 8], 1);
    __syncthreads();
    for (int i = t; i < 512; i += 256)
        lbase[i] = lh[i] ? atomicAdd(&bcur[i], lh[i]) : 0;
    __syncthreads();
    for (int i = lo + t; i < hi; i += 256) {
        int d = dst[i];
        int b = d >> 8;
        int r = atomicAdd(&lr[b], 1);
        binned[lbase[b] + r] = ((unsigned)src[i] << 8) | (unsigned)(d & 255);
    }
}

// One block per bucket: counting sort of <=~4500 edges over 256 local nodes.
__global__ __launch_bounds__(256) void k_bucket(const unsigned* __restrict__ binned,
                                                const int* __restrict__ bbase,
                                                const int* __restrict__ bcnt,
                                                int n, int* __restrict__ offs,
                                                int* __restrict__ cnt,
                                                float* __restrict__ dis,
                                                int* __restrict__ csr) {
    __shared__ int nh[256], nsc[256], nr[256];
    int b = blockIdx.x, t = threadIdx.x;
    int node0 = b << 8;
    int ebase = bbase[b], ecnt = bcnt[b];
    nh[t] = 0; nr[t] = 0;
    __syncthreads();
    for (int j = t; j < ecnt; j += 256)
        atomicAdd(&nh[binned[ebase + j] & 255u], 1);
    __syncthreads();
    int v = nh[t];
    nsc[t] = v;
    __syncthreads();
    for (int o = 1; o < 256; o <<= 1) {
        int x = (t >= o) ? nsc[t - o] : 0;
        __syncthreads();
        nsc[t] += x;
        __syncthreads();
    }
    int ex = nsc[t] - v;
    int d = node0 + t;
    if (d < n) {
        offs[d] = ebase + ex;
        cnt[d]  = v;
        dis[d]  = rsqrtf((float)(v + 1));   // +1 self-loop
    }
    nsc[t] = ex;
    __syncthreads();
    for (int j = t; j < ecnt; j += 256) {
        unsigned ed = binned[ebase + j];
        int ld = ed & 255u;
        int r = atomicAdd(&nr[ld], 1);
        csr[ebase + nsc[ld] + r] = (int)(ed >> 8);
    }
}

// MFMA GEMM: X[n,K] (TI = float or __half) @ W[K,64] (fp32, cvt to fp16)
//   -> H[row][col] = fp16(acc * dis[row]).  fp32 accumulation via MFMA.
// Block: 64 rows, 4 waves; wave computes 16 rows x 64 cols (4 16x16 tiles,
// K/32 mfma steps each). LDS rows padded +8 halves (stride 272B -> 2-way-free
// bank pattern for the b128 fragment reads).
template<int K, typename TI>
__global__ __launch_bounds__(256) void k_gemm_mfma(const TI* __restrict__ X,
                                                   const float* __restrict__ W,
                                                   const float* __restrict__ dis,
                                                   __half* __restrict__ Hh, int n) {
    constexpr int KP = K + 8;
    __shared__ _Float16 As[64 * KP];
    __shared__ _Float16 Bs[64 * KP];   // Bs[n][k] = W[k][n]

    int t = threadIdx.x;
    _Float16* H = (_Float16*)Hh;

    // stage W transposed (once per block)
    for (int i = t; i < K * 64; i += 256) {
        int k = i >> 6, nn = i & 63;
        Bs[nn * KP + k] = (_Float16)W[i];
    }

    // stage A tile: 64 rows x K, 4 threads per row
    int row0  = blockIdx.x * 64;
    int rowIn = t >> 2;
    int seg   = t & 3;
    int grow  = row0 + rowIn;
    constexpr int PER = K / 4;        // elements per thread
    if (sizeof(TI) == 4) {
        const float* Xf = (const float*)X;
        #pragma unroll
        for (int q = 0; q < PER / 4; ++q) {
            float4 v = make_float4(0.f, 0.f, 0.f, 0.f);
            if (grow < n)
                v = *(const float4*)(Xf + (size_t)grow * K + seg * PER + q * 4);
            __half2* dsts = (__half2*)(As + rowIn * KP + seg * PER + q * 4);
            dsts[0] = __floats2half2_rn(v.x, v.y);
            dsts[1] = __floats2half2_rn(v.z, v.w);
        }
    } else {
        const __half* Xh = (const __half*)X;
        #pragma unroll
        for (int q = 0; q < PER / 4; ++q) {
            float2 raw = make_float2(0.f, 0.f);   // 4 halves
            if (grow < n)
                raw = *(const float2*)(Xh + (size_t)grow * K + seg * PER + q * 4);
            *(float2*)(As + rowIn * KP + seg * PER + q * 4) = raw;
        }
    }
    __syncthreads();

    int wv   = t >> 6;
    int lane = t & 63;
    int m    = lane & 15;
    int quad = lane >> 4;
    int r0   = wv * 16;

    f32x4 acc[4] = {};
    const _Float16* Arow = As + (r0 + m) * KP + quad * 8;
    #pragma unroll
    for (int kb = 0; kb < K / 32; ++kb) {
        f16x8 af = *(const f16x8*)(Arow + kb * 32);
        #pragma unroll
        for (int nt = 0; nt < 4; ++nt) {
            f16x8 bf = *(const f16x8*)(Bs + (nt * 16 + m) * KP + quad * 8 + kb * 32);
            acc[nt] = __builtin_amdgcn_mfma_f32_16x16x32_f16(af, bf, acc[nt], 0, 0, 0);
        }
    }

    // epilogue: D col = lane&15, row = quad*4 + reg  [m89-verified mapping]
    float dv[4];
    int   gr[4];
    #pragma unroll
    for (int r = 0; r < 4; ++r) {
        gr[r] = row0 + r0 + quad * 4 + r;
        dv[r] = (gr[r] < n) ? dis[gr[r]] : 0.f;
    }
    #pragma unroll
    for (int nt = 0; nt < 4; ++nt)
        #pragma unroll
        for (int r = 0; r < 4; ++r)
            if (gr[r] < n)
                H[(size_t)gr[r] * 64 + nt * 16 + m] = (_Float16)(acc[nt][r] * dv[r]);
}

__device__ inline void add_row(const __half* __restrict__ hp, int s, int c4,
                               v2f& lo, v2f& hi) {
    float2 raw = *(const float2*)(hp + (size_t)s * 64 + c4);   // 4 halves
    const __half2* p = (const __half2*)&raw;
    float2 l = __half22float2(p[0]);
    float2 h = __half22float2(p[1]);
    lo += (v2f){ l.x, l.y };
    hi += (v2f){ h.x, h.y };
}

// Wave per node: 4 edges x 16 lanes x 4 fp16 channels, fp32 accumulation.
// Indices prefetched + shfl-broadcast in wave-uniform exec (R5 lesson).
// FUSE=false: out is fp16 [n,64] (feeds MFMA GEMM2). FUSE=true: fp32 [n,4].
template<bool FUSE>
__global__ __launch_bounds__(256) void k_gather(const __half* __restrict__ hp,
                                                const int* __restrict__ csr,
                                                const int* __restrict__ off,
                                                const int* __restrict__ cnt,
                                                const float* __restrict__ dis,
                                                const float* __restrict__ bias,
                                                void* __restrict__ outb,
                                                const float* __restrict__ Wfc,
                                                const float* __restrict__ bfc,
                                                int n) {
    int lane = threadIdx.x & 63;
    int wid  = (blockIdx.x * blockDim.x + threadIdx.x) >> 6;
    if (wid >= n) return;                      // wave-uniform (wave per node)
    int d    = wid;
    int esub = lane >> 4;
    int c4   = (lane & 15) * 4;

    int start = off[d], num = cnt[d];
    int idx = (lane < num) ? csr[start + lane] : 0;   // all indices (deg<=64)
    int lim = min(num, 64);

    v2f aL[4] = {}, aH[4] = {};
    if (esub == 0)
        add_row(hp, d, c4, aL[0], aH[0]);      // self-loop

    int j = 0;
    for (; j + 16 <= lim; j += 16) {           // full batches: no clamp needed
        int s0 = __shfl(idx, j + esub);
        int s1 = __shfl(idx, j + 4 + esub);
        int s2 = __shfl(idx, j + 8 + esub);
        int s3 = __shfl(idx, j + 12 + esub);
        add_row(hp, s0, c4, aL[0], aH[0]);
        add_row(hp, s1, c4, aL[1], aH[1]);
        add_row(hp, s2, c4, aL[2], aH[2]);
        add_row(hp, s3, c4, aL[3], aH[3]);
    }
    for (; j < lim; j += 4) {                  // tail: clamp pads to zero row
        int jj = j + esub;                     // jj <= 63 here
        int sr = __shfl(idx, jj);              // uniform exec
        int s  = (jj < lim) ? sr : n;          // zero row at index n
        add_row(hp, s, c4, aL[0], aH[0]);
    }
    for (int j2 = 64; j2 < num; j2 += 4) {     // deg>64: essentially never
        int jj = j2 + esub;
        if (jj < num) {
            int s = csr[start + jj];           // direct load, no shfl
            add_row(hp, s, c4, aL[1], aH[1]);
        }
    }
    v2f sL = (aL[0] + aL[1]) + (aL[2] + aL[3]);
    v2f sH = (aH[0] + aH[1]) + (aH[2] + aH[3]);
    float4 a0 = make_float4(sL.x, sL.y, sH.x, sH.y);
    #pragma unroll
    for (int o = 16; o <= 32; o <<= 1) {
        a0.x += __shfl_xor(a0.x, o);
        a0.y += __shfl_xor(a0.y, o);
        a0.z += __shfl_xor(a0.z, o);
        a0.w += __shfl_xor(a0.w, o);
    }
    float dd = dis[d];
    float4 bb = *(const float4*)(bias + c4);
    float4 o;
    o.x = fmaxf(bb.x + dd * a0.x, 0.f);
    o.y = fmaxf(bb.y + dd * a0.y, 0.f);
    o.z = fmaxf(bb.z + dd * a0.z, 0.f);
    o.w = fmaxf(bb.w + dd * a0.w, 0.f);
    if (!FUSE) {
        if (esub == 0) {
            union { __half2 h[2]; float2 f; } u;
            u.h[0] = __floats2half2_rn(o.x, o.y);
            u.h[1] = __floats2half2_rn(o.z, o.w);
            *(float2*)((__half*)outb + (size_t)d * 64 + c4) = u.f;
        }
    } else {
        const float4* W4 = (const float4*)Wfc;   // row r -> Wfc[r][0..3]
        float4 w0 = W4[c4 + 0], w1 = W4[c4 + 1], w2 = W4[c4 + 2], w3 = W4[c4 + 3];
        float4 p;
        p.x = o.x * w0.x + o.y * w1.x + o.z * w2.x + o.w * w3.x;
        p.y = o.x * w0.y + o.y * w1.y + o.z * w2.y + o.w * w3.y;
        p.z = o.x * w0.z + o.y * w1.z + o.z * w2.z + o.w * w3.z;
        p.w = o.x * w0.w + o.y * w1.w + o.z * w2.w + o.w * w3.w;
        #pragma unroll
        for (int q = 1; q <= 8; q <<= 1) {
            p.x += __shfl_xor(p.x, q);
            p.y += __shfl_xor(p.y, q);
            p.z += __shfl_xor(p.z, q);
            p.w += __shfl_xor(p.w, q);
        }
        if (lane == 0) {
            float4 bf = *(const float4*)bfc;
            float4 r = make_float4(p.x + bf.x, p.y + bf.y, p.z + bf.z, p.w + bf.w);
            ((float4*)outb)[d] = r;
        }
    }
}

static inline size_t align256(size_t x) { return (x + 255) & ~(size_t)255; }

extern "C" void kernel_launch(void* const* d_in, const int* in_sizes, int n_in,
                              void* d_out, int out_size, void* d_ws, size_t ws_size,
                              hipStream_t stream) {
    const float* x   = (const float*)d_in[0];
    const int*   ei  = (const int*)d_in[1];
    const float* W1  = (const float*)d_in[2];
    const float* b1  = (const float*)d_in[3];
    const float* W2  = (const float*)d_in[4];
    const float* b2  = (const float*)d_in[5];
    const float* Wfc = (const float*)d_in[6];
    const float* bfc = (const float*)d_in[7];
    float* out = (float*)d_out;

    int n = in_sizes[0] / 128;   // 100000
    int e = in_sizes[1] / 2;     // 1600000
    const int* src = ei;
    const int* dst = ei + e;

    char* ws = (char*)d_ws;
    size_t p = 0;
    float*    dis    = (float*)   (ws + p); p = align256(p + (size_t)n * 4);
    int*      counts = (int*)     (ws + p); p = align256(p + (size_t)n * 4);
    int*      offs   = (int*)     (ws + p); p = align256(p + (size_t)n * 4);
    int*      bcnt   = (int*)     (ws + p); p = align256(p + 512 * 4);
    int*      bbase  = (int*)     (ws + p); p = align256(p + 512 * 4);
    int*      bcur   = (int*)     (ws + p); p = align256(p + 512 * 4);
    int*      csr    = (int*)     (ws + p); p = align256(p + (size_t)e * 4);
    unsigned* binned = (unsigned*)(ws + p); p = align256(p + (size_t)e * 4);
    __half*   hbuf   = (__half*)  (ws + p); p = align256(p + (size_t)(n + 1) * 64 * 2);
    __half*   a1h    = (__half*)  (ws + p);           // n*64 fp16

    int gb  = (n + 63) / 64;         // mfma gemm tiles (64 rows/block)
    int nbk = (n + 255) / 256;       // buckets = 391

    // CSR build + zero mask-row for the gather
    hipMemsetAsync(bcnt, 0, 512 * sizeof(int), stream);
    hipMemsetAsync(hbuf + (size_t)n * 64, 0, 64 * sizeof(__half), stream);
    k_bcount<<<256, 256, 0, stream>>>(dst, e, bcnt);
    k_bscan<<<1, 512, 0, stream>>>(bcnt, bbase, bcur);
    k_bin<<<256, 256, 0, stream>>>(src, dst, e, bcur, binned);
    k_bucket<<<nbk, 256, 0, stream>>>(binned, bbase, bcnt, n, offs, counts, dis, csr);

    // layer 1: h1' (fp16, MFMA) -> a1 (fp16)
    k_gemm_mfma<128, float><<<gb, 256, 0, stream>>>(x, W1, dis, hbuf, n);
    k_gather<false><<<(n * 64 + 255) / 256, 256, 0, stream>>>(
        hbuf, csr, offs, counts, dis, b1, a1h, nullptr, nullptr, n);

    // layer 2: h2' (fp16, MFMA, reuses hbuf) -> fused final projection
    k_gemm_mfma<64, __half><<<gb, 256, 0, stream>>>(a1h, W2, dis, hbuf, n);
    k_gather<true><<<(n * 64 + 255) / 256, 256, 0, stream>>>(
        hbuf, csr, offs, counts, dis, b2, out, Wfc, bfc, n);
}